// Round 4
// baseline (1269.166 us; speedup 1.0000x reference)
//
#include <hip/hip_runtime.h>
#include <math.h>

#define NN    50000
#define MP    50048    // padded rows (391*128)
#define NEDGE 250000
#define NHOPE 125000
#define ETOT  375000
#define NRELS 500
#define BATCH 65536

typedef __attribute__((ext_vector_type(8))) short bf16x8;
typedef __attribute__((ext_vector_type(4))) float f32x4;

__device__ __forceinline__ unsigned short bf16rne(float f) {
  unsigned u = __float_as_uint(f);
  unsigned r = (u + 0x7FFFu + ((u >> 16) & 1u)) >> 16;
  return (unsigned short)r;
}

// ---------------- l2norm -> bf16 padded (MP x 128) ----------------
__global__ __launch_bounds__(256) void l2norm_bf16(const float* __restrict__ in,
                                                   unsigned short* __restrict__ out) {
  int row  = blockIdx.x * 4 + (threadIdx.x >> 6);
  int lane = threadIdx.x & 63;
  if (row >= MP) return;
  unsigned short* o = out + (size_t)row * 128;
  if (row >= NN) { o[lane] = 0; o[lane + 64] = 0; return; }
  const float* r = in + (size_t)row * 100;
  float v0 = r[lane];
  float v1 = (lane + 64 < 100) ? r[lane + 64] : 0.f;
  float ss = v0 * v0 + v1 * v1;
  #pragma unroll
  for (int off = 1; off < 64; off <<= 1) ss += __shfl_xor(ss, off);
  float inv = 1.f / fmaxf(sqrtf(ss), 1e-12f);
  o[lane] = bf16rne(v0 * inv);
  o[lane + 64] = (lane + 64 < 100) ? bf16rne(v1 * inv) : (unsigned short)0;
}

// ---------------- bf16 MFMA GEMM: C[i,j] = sum_k A[i,k]*B[j,k], j<200 ----------------
// A: MP x KP bf16 (k-contig). B: 208 x KP bf16 (k-contig). C: f32, ldc.
// block = 256 thr (4 waves), covers 128 rows; 13 col tiles of 16.
template<int KP>
__global__ __launch_bounds__(256) void gemm_bf16(const unsigned short* __restrict__ A,
                                                 const unsigned short* __restrict__ B,
                                                 float* __restrict__ C, int M, int ldc) {
  int wave = threadIdx.x >> 6, lane = threadIdx.x & 63;
  int rb = blockIdx.x * 128 + wave * 32;
  int rl = lane & 15;
  int kq = (lane >> 4) * 8;
  const unsigned short* a0p = A + (size_t)(rb + rl) * KP + kq;
  const unsigned short* a1p = a0p + (size_t)16 * KP;
  const unsigned short* bp  = B + (size_t)rl * KP + kq;
  f32x4 acc[2][13];
  #pragma unroll
  for (int i = 0; i < 2; ++i)
    #pragma unroll
    for (int t = 0; t < 13; ++t) acc[i][t] = (f32x4){0.f, 0.f, 0.f, 0.f};
  #pragma unroll 2
  for (int ks = 0; ks < KP; ks += 32) {
    bf16x8 a0 = *(const bf16x8*)(a0p + ks);
    bf16x8 a1 = *(const bf16x8*)(a1p + ks);
    #pragma unroll
    for (int t = 0; t < 13; ++t) {
      bf16x8 b = *(const bf16x8*)(bp + (size_t)t * 16 * KP + ks);
      acc[0][t] = __builtin_amdgcn_mfma_f32_16x16x32_bf16(a0, b, acc[0][t], 0, 0, 0);
      acc[1][t] = __builtin_amdgcn_mfma_f32_16x16x32_bf16(a1, b, acc[1][t], 0, 0, 0);
    }
  }
  int rg = (lane >> 4) * 4;
  #pragma unroll
  for (int rt = 0; rt < 2; ++rt) {
    int row0 = rb + rt * 16 + rg;
    #pragma unroll
    for (int t = 0; t < 13; ++t) {
      int col = t * 16 + rl;
      if (col < 200) {
        #pragma unroll
        for (int g = 0; g < 4; ++g) {
          int row = row0 + g;
          if (row < M) C[(size_t)row * ldc + col] = acc[rt][t][g];
        }
      }
    }
  }
}

// ---------------- weight conversion to bf16 k-major padded ----------------
// stacked two-head slices of a_heads: rows 0..99 head0, 100..199 head1; K=100->128
__global__ __launch_bounds__(256) void convB1(const float* __restrict__ ah, int koff,
                                              unsigned short* __restrict__ dst) {
  int idx = blockIdx.x * 256 + threadIdx.x;
  if (idx >= 208 * 128) return;
  int j = idx >> 7, k = idx & 127;
  float v = 0.f;
  if (j < 200 && k < 100) {
    const float* s = ah + ((j < 100) ? 0 : 30000) + (j % 100) * 300 + koff;
    v = s[k];
  }
  dst[idx] = bf16rne(v);
}

__global__ __launch_bounds__(256) void convBg(const float* __restrict__ src, int wsj, int wsk,
                                              int rows, int K, int Kp,
                                              unsigned short* __restrict__ dst) {
  int idx = blockIdx.x * 256 + threadIdx.x;
  if (idx >= 208 * Kp) return;
  int j = idx / Kp, k = idx - j * Kp;
  float v = (j < rows && k < K) ? src[(size_t)j * wsj + (size_t)k * wsk] : 0.f;
  dst[idx] = bf16rne(v);
}

// ---------------- f32 GEMM (small, rel matrices) ----------------
__global__ __launch_bounds__(256) void gemm2_f32(const float* __restrict__ A, int M, int Kd, int lda,
                                                 const float* __restrict__ W, int wsj, int wsk,
                                                 float* __restrict__ C, int ldc, int Ncols, int col0) {
  __shared__ float As[16][132];
  __shared__ float Bs[16][68];
  int tid = threadIdx.x;
  int tx = tid & 15, ty = tid >> 4;
  int row0 = blockIdx.y * 128;
  int colb = blockIdx.x * 64;
  float acc[8][4];
  #pragma unroll
  for (int i = 0; i < 8; ++i)
    #pragma unroll
    for (int j = 0; j < 4; ++j) acc[i][j] = 0.f;
  for (int kt = 0; kt < Kd; kt += 16) {
    #pragma unroll
    for (int l = 0; l < 8; ++l) {
      int idx = tid + l * 256;
      int m = idx >> 4, k = idx & 15;
      int gm = row0 + m, gk = kt + k;
      As[k][m] = (gm < M && gk < Kd) ? A[(size_t)gm * lda + gk] : 0.f;
    }
    #pragma unroll
    for (int l = 0; l < 4; ++l) {
      int idx = tid + l * 256;
      int j = idx >> 4, k = idx & 15;
      int gj = colb + j, gk = kt + k;
      Bs[k][j] = (gj < Ncols && gk < Kd) ? W[(size_t)gj * wsj + (size_t)gk * wsk] : 0.f;
    }
    __syncthreads();
    #pragma unroll
    for (int k = 0; k < 16; ++k) {
      float4 bv = *(const float4*)&Bs[k][tx * 4];
      float4 a0 = *(const float4*)&As[k][ty * 8];
      float4 a1 = *(const float4*)&As[k][ty * 8 + 4];
      float av[8] = {a0.x, a0.y, a0.z, a0.w, a1.x, a1.y, a1.z, a1.w};
      float bb[4] = {bv.x, bv.y, bv.z, bv.w};
      #pragma unroll
      for (int i = 0; i < 8; ++i)
        #pragma unroll
        for (int j = 0; j < 4; ++j)
          acc[i][j] += av[i] * bb[j];
    }
    __syncthreads();
  }
  int gj0 = colb + tx * 4;
  #pragma unroll
  for (int i = 0; i < 8; ++i) {
    int gm = row0 + ty * 8 + i;
    if (gm >= M) continue;
    float* cp = C + (size_t)gm * ldc + col0;
    #pragma unroll
    for (int j = 0; j < 4; ++j) if (gj0 + j < Ncols) cp[gj0 + j] = acc[i][j];
  }
}

// ---------------- per-row dots ----------------
__global__ __launch_bounds__(256) void dot2h(const float* __restrict__ P, const float* __restrict__ a2,
                                             float* __restrict__ outp, int M) {
  int row  = blockIdx.x * 4 + (threadIdx.x >> 6);
  int lane = threadIdx.x & 63;
  if (row >= M) return;
  const float* pr = P + (size_t)row * 200;
  float s0 = 0.f, s1 = 0.f;
  for (int k = lane; k < 100; k += 64) {
    s0 += pr[k] * a2[k];
    s1 += pr[100 + k] * a2[100 + k];
  }
  #pragma unroll
  for (int off = 1; off < 64; off <<= 1) { s0 += __shfl_xor(s0, off); s1 += __shfl_xor(s1, off); }
  if (lane == 0) { outp[row * 2] = s0; outp[row * 2 + 1] = s1; }
}

__global__ __launch_bounds__(256) void dot1(const float* __restrict__ P, const float* __restrict__ a2,
                                            float* __restrict__ outp, int M) {
  int row  = blockIdx.x * 4 + (threadIdx.x >> 6);
  int lane = threadIdx.x & 63;
  if (row >= M) return;
  const float* pr = P + (size_t)row * 200;
  float s = 0.f;
  for (int k = lane; k < 200; k += 64) s += pr[k] * a2[k];
  #pragma unroll
  for (int off = 1; off < 64; off <<= 1) s += __shfl_xor(s, off);
  if (lane == 0) outp[row] = s;
}

// ---------------- CSR build ----------------
__global__ __launch_bounds__(256) void histk(const int* __restrict__ el, const int* __restrict__ tin,
                                             int* __restrict__ deg) {
  int i = blockIdx.x * 256 + threadIdx.x;
  if (i >= ETOT) return;
  int e0 = (i < NEDGE) ? el[i] : tin[(size_t)(i - NEDGE) * 4 + 3];
  atomicAdd(&deg[e0], 1);
}

__global__ __launch_bounds__(256) void scanA(const int* __restrict__ deg, int* __restrict__ bsum, int n) {
  __shared__ int s[256];
  int t = threadIdx.x;
  int i = blockIdx.x * 256 + t;
  s[t] = (i < n) ? deg[i] : 0;
  __syncthreads();
  for (int off = 128; off > 0; off >>= 1) {
    if (t < off) s[t] += s[t + off];
    __syncthreads();
  }
  if (t == 0) bsum[blockIdx.x] = s[0];
}

__global__ __launch_bounds__(256) void scanB(int* __restrict__ bsum, int nb) {
  __shared__ int s[256];
  int t = threadIdx.x;
  int v = (t < nb) ? bsum[t] : 0;
  s[t] = v;
  __syncthreads();
  for (int off = 1; off < 256; off <<= 1) {
    int add = (t >= off) ? s[t - off] : 0;
    __syncthreads();
    s[t] += add;
    __syncthreads();
  }
  if (t < nb) bsum[t] = s[t] - v;  // exclusive
}

__global__ __launch_bounds__(256) void scanC(const int* __restrict__ deg, const int* __restrict__ bsum,
                                             int* __restrict__ offs, int* __restrict__ pos, int n, int total) {
  __shared__ int s[256];
  int t = threadIdx.x;
  int i = blockIdx.x * 256 + t;
  int v = (i < n) ? deg[i] : 0;
  s[t] = v;
  __syncthreads();
  for (int off = 1; off < 256; off <<= 1) {
    int add = (t >= off) ? s[t - off] : 0;
    __syncthreads();
    s[t] += add;
    __syncthreads();
  }
  if (i < n) {
    int e = bsum[blockIdx.x] + s[t] - v;
    offs[i] = e;
    pos[i]  = e;
  }
  if (i == 0) offs[n] = total;
}

__global__ __launch_bounds__(256) void scatterk(const int* __restrict__ el, const int* __restrict__ et,
                                                const int* __restrict__ tin,
                                                int* __restrict__ pos, int2* __restrict__ edata) {
  int i = blockIdx.x * 256 + threadIdx.x;
  if (i >= ETOT) return;
  int e0, e1, t1, t2f;
  if (i < NEDGE) {
    e0 = el[i]; e1 = el[NEDGE + i]; t1 = et[i]; t2f = 0;
  } else {
    const int* q = tin + (size_t)(i - NEDGE) * 4;
    e0 = q[3]; e1 = q[0]; t1 = q[1]; t2f = q[2] + 1;
  }
  int slot = atomicAdd(&pos[e0], 1);
  edata[slot] = make_int2(e1 | (t1 << 16), t2f);
}

__global__ __launch_bounds__(256) void buildLists(const int* __restrict__ offs,
                                                  int* __restrict__ lightL, int* __restrict__ heavyL,
                                                  int* __restrict__ cnts) {
  int i = blockIdx.x * 256 + threadIdx.x;
  if (i >= NN) return;
  int d = offs[i + 1] - offs[i];
  if (d > 64) heavyL[atomicAdd(&cnts[1], 1)] = i;
  else        lightL[atomicAdd(&cnts[0], 1)] = i;
}

// ---------------- layer-1 gather: light (wave/node) ----------------
__global__ __launch_bounds__(256) void gather1L(const int* __restrict__ lightL, const int* __restrict__ cnts,
    const int* __restrict__ offs, const int2* __restrict__ edata,
    const float* __restrict__ srcp, const float* __restrict__ dstp, const float* __restrict__ relp,
    const float* __restrict__ ssrc, const float* __restrict__ sdst, const float* __restrict__ srel,
    unsigned short* __restrict__ xbf) {
  int widx = blockIdx.x * 4 + (threadIdx.x >> 6);
  if (widx >= cnts[0]) return;
  int node = lightL[widx];
  int lane = threadIdx.x & 63;
  int s = offs[node], e = offs[node + 1];
  float s00 = ssrc[node * 2], s01 = ssrc[node * 2 + 1];
  int c0 = lane, c1 = lane + 64, c2 = lane + 128, c3 = lane + 192;
  float acc0 = 0.f, acc1 = 0.f, acc2 = 0.f, acc3 = 0.f, rs0 = 0.f, rs1 = 0.f;
  for (int q = s; q < e; ++q) {
    int2 ed = edata[q];
    unsigned w0 = (unsigned)ed.x;
    int e1 = (int)(w0 & 0xFFFFu);
    int t1 = (int)(w0 >> 16);
    int t2f = ed.y;
    float p0 = s00 + sdst[e1 * 2]     + srel[t1 * 2];
    float p1 = s01 + sdst[e1 * 2 + 1] + srel[t1 * 2 + 1];
    const float* rd = dstp + (size_t)e1 * 200;
    const float* r1 = relp + t1 * 200;
    float m0, m1, m2, m3;
    if (t2f) {
      int t2 = t2f - 1;
      p0 += srel[t2 * 2]; p1 += srel[t2 * 2 + 1];
      const float* r2 = relp + t2 * 200;
      m0 = rd[c0] + r1[c0] + r2[c0];
      m1 = rd[c1] + r1[c1] + r2[c1];
      m2 = rd[c2] + r1[c2] + r2[c2];
      m3 = (c3 < 200) ? rd[c3] + r1[c3] + r2[c3] : 0.f;
    } else {
      m0 = rd[c0] + r1[c0];
      m1 = rd[c1] + r1[c1];
      m2 = rd[c2] + r1[c2];
      m3 = (c3 < 200) ? rd[c3] + r1[c3] : 0.f;
    }
    p0 = (p0 > 0.f) ? p0 : 0.2f * p0;
    p1 = (p1 > 0.f) ? p1 : 0.2f * p1;
    float ee0 = __expf(-p0), ee1 = __expf(-p1);
    rs0 += ee0; rs1 += ee1;
    acc0 += ee0 * m0;
    acc1 += ((c1 < 100) ? ee0 : ee1) * m1;
    acc2 += ee1 * m2;
    acc3 += ee1 * m3;
  }
  bool has = (e > s);
  float inv0 = has ? 1.f / rs0 : 0.f;
  float inv1 = has ? 1.f / rs1 : 0.f;
  const float* sp = srcp + (size_t)node * 200;
  unsigned short* xo = xbf + (size_t)node * 224;
  float v;
  v = has ? sp[c0] + acc0 * inv0 : 0.f;                       v = (v > 0.f) ? v : expm1f(v); xo[c0] = bf16rne(v);
  v = has ? sp[c1] + acc1 * ((c1 < 100) ? inv0 : inv1) : 0.f; v = (v > 0.f) ? v : expm1f(v); xo[c1] = bf16rne(v);
  v = has ? sp[c2] + acc2 * inv1 : 0.f;                       v = (v > 0.f) ? v : expm1f(v); xo[c2] = bf16rne(v);
  if (c3 < 200) {
    v = has ? sp[c3] + acc3 * inv1 : 0.f;
    v = (v > 0.f) ? v : expm1f(v);
    xo[c3] = bf16rne(v);
  } else if (c3 < 224) {
    xo[c3] = 0;
  }
}

// ---------------- layer-1 gather: heavy (block/node, 8 waves) ----------------
__global__ __launch_bounds__(512) void gather1H(const int* __restrict__ heavyL, const int* __restrict__ cnts,
    const int* __restrict__ offs, const int2* __restrict__ edata,
    const float* __restrict__ srcp, const float* __restrict__ dstp, const float* __restrict__ relp,
    const float* __restrict__ ssrc, const float* __restrict__ sdst, const float* __restrict__ srel,
    unsigned short* __restrict__ xbf) {
  __shared__ float part[8][208];
  if (blockIdx.x >= (unsigned)cnts[1]) return;
  int node = heavyL[blockIdx.x];
  int w = threadIdx.x >> 6, lane = threadIdx.x & 63;
  int s = offs[node], e = offs[node + 1];
  float s00 = ssrc[node * 2], s01 = ssrc[node * 2 + 1];
  int c0 = lane, c1 = lane + 64, c2 = lane + 128, c3 = lane + 192;
  float acc0 = 0.f, acc1 = 0.f, acc2 = 0.f, acc3 = 0.f, rs0 = 0.f, rs1 = 0.f;
  for (int q = s + w; q < e; q += 8) {
    int2 ed = edata[q];
    unsigned w0 = (unsigned)ed.x;
    int e1 = (int)(w0 & 0xFFFFu);
    int t1 = (int)(w0 >> 16);
    int t2f = ed.y;
    float p0 = s00 + sdst[e1 * 2]     + srel[t1 * 2];
    float p1 = s01 + sdst[e1 * 2 + 1] + srel[t1 * 2 + 1];
    const float* rd = dstp + (size_t)e1 * 200;
    const float* r1 = relp + t1 * 200;
    float m0, m1, m2, m3;
    if (t2f) {
      int t2 = t2f - 1;
      p0 += srel[t2 * 2]; p1 += srel[t2 * 2 + 1];
      const float* r2 = relp + t2 * 200;
      m0 = rd[c0] + r1[c0] + r2[c0];
      m1 = rd[c1] + r1[c1] + r2[c1];
      m2 = rd[c2] + r1[c2] + r2[c2];
      m3 = (c3 < 200) ? rd[c3] + r1[c3] + r2[c3] : 0.f;
    } else {
      m0 = rd[c0] + r1[c0];
      m1 = rd[c1] + r1[c1];
      m2 = rd[c2] + r1[c2];
      m3 = (c3 < 200) ? rd[c3] + r1[c3] : 0.f;
    }
    p0 = (p0 > 0.f) ? p0 : 0.2f * p0;
    p1 = (p1 > 0.f) ? p1 : 0.2f * p1;
    float ee0 = __expf(-p0), ee1 = __expf(-p1);
    rs0 += ee0; rs1 += ee1;
    acc0 += ee0 * m0;
    acc1 += ((c1 < 100) ? ee0 : ee1) * m1;
    acc2 += ee1 * m2;
    acc3 += ee1 * m3;
  }
  part[w][c0] = acc0; part[w][c1] = acc1; part[w][c2] = acc2;
  if (c3 < 200) part[w][c3] = acc3;
  if (lane == 0) { part[w][200] = rs0; part[w][201] = rs1; }
  __syncthreads();
  int t = threadIdx.x;
  if (t < 224) {
    unsigned short outv = 0;
    if (t < 200) {
      float a = 0.f, r0 = 0.f, r1 = 0.f;
      #pragma unroll
      for (int wv = 0; wv < 8; ++wv) { a += part[wv][t]; r0 += part[wv][200]; r1 += part[wv][201]; }
      float inv = (t < 100) ? 1.f / r0 : 1.f / r1;
      float v = srcp[(size_t)node * 200 + t] + a * inv;
      v = (v > 0.f) ? v : expm1f(v);
      outv = bf16rne(v);
    }
    xbf[(size_t)node * 224 + t] = outv;
  }
}

// ---------------- layer-2 gather: light ----------------
__global__ __launch_bounds__(256) void gather2L(const int* __restrict__ lightL, const int* __restrict__ cnts,
    const int* __restrict__ offs, const int2* __restrict__ edata,
    const float* __restrict__ srcp, const float* __restrict__ dstp, const float* __restrict__ relp,
    const float* __restrict__ ssrc, const float* __restrict__ sdst, const float* __restrict__ srel,
    float* __restrict__ hout) {
  int widx = blockIdx.x * 4 + (threadIdx.x >> 6);
  if (widx >= cnts[0]) return;
  int node = lightL[widx];
  int lane = threadIdx.x & 63;
  int s = offs[node], e = offs[node + 1];
  float s0 = ssrc[node];
  int c0 = lane, c1 = lane + 64, c2 = lane + 128, c3 = lane + 192;
  float acc0 = 0.f, acc1 = 0.f, acc2 = 0.f, acc3 = 0.f, rs = 0.f;
  for (int q = s; q < e; ++q) {
    int2 ed = edata[q];
    unsigned w0 = (unsigned)ed.x;
    int e1 = (int)(w0 & 0xFFFFu);
    int t1 = (int)(w0 >> 16);
    int t2f = ed.y;
    float p = s0 + sdst[e1] + srel[t1];
    const float* rd = dstp + (size_t)e1 * 200;
    const float* r1 = relp + t1 * 200;
    float m0, m1, m2, m3;
    if (t2f) {
      int t2 = t2f - 1;
      p += srel[t2];
      const float* r2 = relp + t2 * 200;
      m0 = rd[c0] + r1[c0] + r2[c0];
      m1 = rd[c1] + r1[c1] + r2[c1];
      m2 = rd[c2] + r1[c2] + r2[c2];
      m3 = (c3 < 200) ? rd[c3] + r1[c3] + r2[c3] : 0.f;
    } else {
      m0 = rd[c0] + r1[c0];
      m1 = rd[c1] + r1[c1];
      m2 = rd[c2] + r1[c2];
      m3 = (c3 < 200) ? rd[c3] + r1[c3] : 0.f;
    }
    p = (p > 0.f) ? p : 0.2f * p;
    float ee = __expf(-p);
    rs += ee;
    acc0 += ee * m0; acc1 += ee * m1; acc2 += ee * m2; acc3 += ee * m3;
  }
  bool has = (e > s);
  float inv = has ? 1.f / rs : 0.f;
  const float* sp = srcp + (size_t)node * 200;
  float* ho = hout + (size_t)node * 200;
  float v;
  v = has ? sp[c0] + acc0 * inv : 0.f; ho[c0] = (v > 0.f) ? v : expm1f(v);
  v = has ? sp[c1] + acc1 * inv : 0.f; ho[c1] = (v > 0.f) ? v : expm1f(v);
  v = has ? sp[c2] + acc2 * inv : 0.f; ho[c2] = (v > 0.f) ? v : expm1f(v);
  if (c3 < 200) {
    v = has ? sp[c3] + acc3 * inv : 0.f;
    ho[c3] = (v > 0.f) ? v : expm1f(v);
  }
}

// ---------------- layer-2 gather: heavy ----------------
__global__ __launch_bounds__(512) void gather2H(const int* __restrict__ heavyL, const int* __restrict__ cnts,
    const int* __restrict__ offs, const int2* __restrict__ edata,
    const float* __restrict__ srcp, const float* __restrict__ dstp, const float* __restrict__ relp,
    const float* __restrict__ ssrc, const float* __restrict__ sdst, const float* __restrict__ srel,
    float* __restrict__ hout) {
  __shared__ float part[8][208];
  if (blockIdx.x >= (unsigned)cnts[1]) return;
  int node = heavyL[blockIdx.x];
  int w = threadIdx.x >> 6, lane = threadIdx.x & 63;
  int s = offs[node], e = offs[node + 1];
  float s0 = ssrc[node];
  int c0 = lane, c1 = lane + 64, c2 = lane + 128, c3 = lane + 192;
  float acc0 = 0.f, acc1 = 0.f, acc2 = 0.f, acc3 = 0.f, rs = 0.f;
  for (int q = s + w; q < e; q += 8) {
    int2 ed = edata[q];
    unsigned w0 = (unsigned)ed.x;
    int e1 = (int)(w0 & 0xFFFFu);
    int t1 = (int)(w0 >> 16);
    int t2f = ed.y;
    float p = s0 + sdst[e1] + srel[t1];
    const float* rd = dstp + (size_t)e1 * 200;
    const float* r1 = relp + t1 * 200;
    float m0, m1, m2, m3;
    if (t2f) {
      int t2 = t2f - 1;
      p += srel[t2];
      const float* r2 = relp + t2 * 200;
      m0 = rd[c0] + r1[c0] + r2[c0];
      m1 = rd[c1] + r1[c1] + r2[c1];
      m2 = rd[c2] + r1[c2] + r2[c2];
      m3 = (c3 < 200) ? rd[c3] + r1[c3] + r2[c3] : 0.f;
    } else {
      m0 = rd[c0] + r1[c0];
      m1 = rd[c1] + r1[c1];
      m2 = rd[c2] + r1[c2];
      m3 = (c3 < 200) ? rd[c3] + r1[c3] : 0.f;
    }
    p = (p > 0.f) ? p : 0.2f * p;
    float ee = __expf(-p);
    rs += ee;
    acc0 += ee * m0; acc1 += ee * m1; acc2 += ee * m2; acc3 += ee * m3;
  }
  part[w][c0] = acc0; part[w][c1] = acc1; part[w][c2] = acc2;
  if (c3 < 200) part[w][c3] = acc3;
  if (lane == 0) part[w][200] = rs;
  __syncthreads();
  int t = threadIdx.x;
  if (t < 200) {
    float a = 0.f, r = 0.f;
    #pragma unroll
    for (int wv = 0; wv < 8; ++wv) { a += part[wv][t]; r += part[wv][200]; }
    float v = srcp[(size_t)node * 200 + t] + a / r;
    hout[(size_t)node * 200 + t] = (v > 0.f) ? v : expm1f(v);
  }
}

// ---------------- pad xbf rows [NN, MP) ----------------
__global__ __launch_bounds__(256) void padx(unsigned short* __restrict__ xbf) {
  int i = blockIdx.x * 256 + threadIdx.x;
  if (i < (MP - NN) * 224) xbf[(size_t)NN * 224 + i] = 0;
}

// ---------------- mask scatter ----------------
__global__ __launch_bounds__(256) void maskset(const int* __restrict__ bi, float* __restrict__ maskA) {
  int t = blockIdx.x * 256 + threadIdx.x;
  if (t < BATCH) maskA[bi[t * 3 + 2]] = 1.0f;
}

// ---------------- final: out = l2norm(xw + mask*h2), in place on d_out ----------------
__global__ __launch_bounds__(256) void finalk2(const float* __restrict__ xw, const float* __restrict__ h2,
                                               const float* __restrict__ maskA, float* __restrict__ out) {
  int row  = blockIdx.x * 4 + (threadIdx.x >> 6);
  int lane = threadIdx.x & 63;
  if (row >= NN) return;
  float m = maskA[row];
  const float* xr = xw + (size_t)row * 200;
  const float* hr = h2 + (size_t)row * 200;
  int c0 = lane, c1 = lane + 64, c2 = lane + 128, c3 = lane + 192;
  float v0 = xr[c0] + m * hr[c0];
  float v1 = xr[c1] + m * hr[c1];
  float v2 = xr[c2] + m * hr[c2];
  float v3 = (c3 < 200) ? xr[c3] + m * hr[c3] : 0.f;
  float ss = v0 * v0 + v1 * v1 + v2 * v2 + v3 * v3;
  #pragma unroll
  for (int off = 1; off < 64; off <<= 1) ss += __shfl_xor(ss, off);
  float inv = 1.f / fmaxf(sqrtf(ss), 1e-12f);
  float* o = out + (size_t)row * 200;
  o[c0] = v0 * inv; o[c1] = v1 * inv; o[c2] = v2 * inv;
  if (c3 < 200) o[c3] = v3 * inv;
}

extern "C" void kernel_launch(void* const* d_in, const int* in_sizes, int n_in,
                              void* d_out, int out_size, void* d_ws, size_t ws_size,
                              hipStream_t stream) {
  (void)in_sizes; (void)n_in; (void)out_size; (void)ws_size;
  const float* ent      = (const float*)d_in[0];
  const float* rel      = (const float*)d_in[1];
  const float* a_heads  = (const float*)d_in[3];
  const float* a2_heads = (const float*)d_in[4];
  const float* W_gat    = (const float*)d_in[5];
  const float* a_out    = (const float*)d_in[6];
  const float* a2_out   = (const float*)d_in[7];
  const float* W_ent    = (const float*)d_in[8];
  const int* edge_list  = (const int*)d_in[9];
  const int* edge_type  = (const int*)d_in[10];
  const int* tin        = (const int*)d_in[11];
  const int* binp       = (const int*)d_in[12];

  float* out    = (float*)d_out;
  float* outrel = out + 10000000;     // (500,200)

  float* ws    = (float*)d_ws;
  float* bufS  = ws;                  // 10M: srcp1 -> srcp2 -> h2 (in place)
  float* bufD  = ws + 10000000;       // 10M: dstp1 -> dstp2
  float* relp1 = ws + 20000000;       // 100k
  float* relp2 = ws + 20100000;       // 100k
  float* ssrc1 = ws + 20200000;       // 100k (N*2)
  float* sdst1 = ws + 20300000;       // 100k
  float* s2src = ws + 20400000;       // 50k
  float* s2dst = ws + 20450000;       // 50k
  float* srel1 = ws + 20500000;       // 1000
  float* s2rel = ws + 20501000;       // 500
  float* maskA = ws + 20502000;       // 50k
  unsigned short* x0nbf = (unsigned short*)(ws + 20560000); // MP*128 bf16
  unsigned short* xbf   = (unsigned short*)(ws + 23800000); // MP*224 bf16
  unsigned short* B1s   = (unsigned short*)(ws + 29500000); // 208*128
  unsigned short* B1d   = (unsigned short*)(ws + 29520000);
  unsigned short* Bxw   = (unsigned short*)(ws + 29540000);
  unsigned short* B2s   = (unsigned short*)(ws + 29560000); // 208*224
  unsigned short* B2d   = (unsigned short*)(ws + 29590000);
  int* ibase  = (int*)(ws + 29700000);
  int* deg    = ibase;                // 50k
  int* offs   = ibase + 50000;        // 50k+1
  int* pos    = ibase + 100016;       // 50k
  int* bsum   = ibase + 150016;       // 256
  int* cnts   = ibase + 150272;       // 2
  int* lightL = ibase + 150280;       // 50k
  int* heavyL = ibase + 200280;       // 50k
  int2* edata = (int2*)(ibase + 250288); // 375k int2

  hipMemsetAsync(deg,   0, (size_t)NN * 4, stream);
  hipMemsetAsync(maskA, 0, (size_t)NN * 4, stream);
  hipMemsetAsync(cnts,  0, 8, stream);

  l2norm_bf16<<<12512, 256, 0, stream>>>(ent, x0nbf);

  // CSR + lists
  histk<<<(ETOT + 255) / 256, 256, 0, stream>>>(edge_list, tin, deg);
  scanA<<<196, 256, 0, stream>>>(deg, bsum, NN);
  scanB<<<1, 256, 0, stream>>>(bsum, 196);
  scanC<<<196, 256, 0, stream>>>(deg, bsum, offs, pos, NN, ETOT);
  scatterk<<<(ETOT + 255) / 256, 256, 0, stream>>>(edge_list, edge_type, tin, pos, edata);
  buildLists<<<196, 256, 0, stream>>>(offs, lightL, heavyL, cnts);

  // weight conversion
  convB1<<<104, 256, 0, stream>>>(a_heads, 0,   B1s);
  convB1<<<104, 256, 0, stream>>>(a_heads, 100, B1d);
  convBg<<<104, 256, 0, stream>>>(W_ent, 1, 200, 200, 100, 128, Bxw);
  convBg<<<182, 256, 0, stream>>>(a_out,       600, 1, 200, 200, 224, B2s);
  convBg<<<182, 256, 0, stream>>>(a_out + 200, 600, 1, 200, 200, 224, B2d);

  // layer-1 projections + xw (bf16 MFMA)
  gemm_bf16<128><<<391, 256, 0, stream>>>(x0nbf, B1s, bufS, NN, 200);
  gemm_bf16<128><<<391, 256, 0, stream>>>(x0nbf, B1d, bufD, NN, 200);
  gemm_bf16<128><<<391, 256, 0, stream>>>(x0nbf, Bxw, out,  NN, 200);

  // rel projections (f32, small)
  dim3 g2(2, 4);
  gemm2_f32<<<g2, 256, 0, stream>>>(rel, NRELS, 100, 100, a_heads + 200,         300, 1, relp1, 200, 100, 0);
  gemm2_f32<<<g2, 256, 0, stream>>>(rel, NRELS, 100, 100, a_heads + 30000 + 200, 300, 1, relp1, 200, 100, 100);

  dot2h<<<12500, 256, 0, stream>>>(bufS, a2_heads, ssrc1, NN);
  dot2h<<<12500, 256, 0, stream>>>(bufD, a2_heads, sdst1, NN);
  dot2h<<<125,   256, 0, stream>>>(relp1, a2_heads, srel1, NRELS);

  gather1L<<<12500, 256, 0, stream>>>(lightL, cnts, offs, edata, bufS, bufD, relp1, ssrc1, sdst1, srel1, xbf);
  gather1H<<<5792, 512, 0, stream>>>(heavyL, cnts, offs, edata, bufS, bufD, relp1, ssrc1, sdst1, srel1, xbf);
  padx<<<42, 256, 0, stream>>>(xbf);

  // layer-2 projections (bf16 MFMA, overwrite bufS/bufD)
  gemm_bf16<224><<<391, 256, 0, stream>>>(xbf, B2s, bufS, NN, 200);
  gemm_bf16<224><<<391, 256, 0, stream>>>(xbf, B2d, bufD, NN, 200);

  // out_relation_1 and relp2 (f32, small)
  dim3 g3(4, 4);
  gemm2_f32<<<g3, 256, 0, stream>>>(rel, NRELS, 100, 100, W_gat, 1, 200, outrel, 200, 200, 0);
  gemm2_f32<<<g3, 256, 0, stream>>>(outrel, NRELS, 200, 200, a_out + 400, 600, 1, relp2, 200, 200, 0);

  dot1<<<12500, 256, 0, stream>>>(bufS, a2_out, s2src, NN);
  dot1<<<12500, 256, 0, stream>>>(bufD, a2_out, s2dst, NN);
  dot1<<<125,   256, 0, stream>>>(relp2, a2_out, s2rel, NRELS);

  maskset<<<256, 256, 0, stream>>>(binp, maskA);

  gather2L<<<12500, 256, 0, stream>>>(lightL, cnts, offs, edata, bufS, bufD, relp2, s2src, s2dst, s2rel, bufS);
  gather2H<<<5792, 512, 0, stream>>>(heavyL, cnts, offs, edata, bufS, bufD, relp2, s2src, s2dst, s2rel, bufS);

  finalk2<<<12500, 256, 0, stream>>>(out, bufS, maskA, out);
}

// Round 5
// 703.769 us; speedup vs baseline: 1.8034x; 1.8034x over previous
//
#include <hip/hip_runtime.h>
#include <math.h>

#define NN    50000
#define MP    50048    // padded rows (391*128)
#define NEDGE 250000
#define NHOPE 125000
#define ETOT  375000
#define NRELS 500
#define BATCH 65536

typedef __attribute__((ext_vector_type(8))) short bf16x8;
typedef __attribute__((ext_vector_type(4))) float f32x4;

__device__ __forceinline__ unsigned short bf16rne(float f) {
  unsigned u = __float_as_uint(f);
  unsigned r = (u + 0x7FFFu + ((u >> 16) & 1u)) >> 16;
  return (unsigned short)r;
}

// ---------------- l2norm -> bf16 padded (MP x 128) ----------------
__global__ __launch_bounds__(256) void l2norm_bf16(const float* __restrict__ in,
                                                   unsigned short* __restrict__ out) {
  int row  = blockIdx.x * 4 + (threadIdx.x >> 6);
  int lane = threadIdx.x & 63;
  if (row >= MP) return;
  unsigned short* o = out + (size_t)row * 128;
  if (row >= NN) { o[lane] = 0; o[lane + 64] = 0; return; }
  const float* r = in + (size_t)row * 100;
  float v0 = r[lane];
  float v1 = (lane + 64 < 100) ? r[lane + 64] : 0.f;
  float ss = v0 * v0 + v1 * v1;
  #pragma unroll
  for (int off = 1; off < 64; off <<= 1) ss += __shfl_xor(ss, off);
  float inv = 1.f / fmaxf(sqrtf(ss), 1e-12f);
  o[lane] = bf16rne(v0 * inv);
  o[lane + 64] = (lane + 64 < 100) ? bf16rne(v1 * inv) : (unsigned short)0;
}

// ---------------- bf16 MFMA GEMM: C[i,j] = sum_k A[i,k]*B[j,k], j<200 ----------------
template<int KP>
__global__ __launch_bounds__(256) void gemm_bf16(const unsigned short* __restrict__ A,
                                                 const unsigned short* __restrict__ B,
                                                 float* __restrict__ C, int M, int ldc) {
  int wave = threadIdx.x >> 6, lane = threadIdx.x & 63;
  int rb = blockIdx.x * 128 + wave * 32;
  int rl = lane & 15;
  int kq = (lane >> 4) * 8;
  const unsigned short* a0p = A + (size_t)(rb + rl) * KP + kq;
  const unsigned short* a1p = a0p + (size_t)16 * KP;
  const unsigned short* bp  = B + (size_t)rl * KP + kq;
  f32x4 acc[2][13];
  #pragma unroll
  for (int i = 0; i < 2; ++i)
    #pragma unroll
    for (int t = 0; t < 13; ++t) acc[i][t] = (f32x4){0.f, 0.f, 0.f, 0.f};
  #pragma unroll 2
  for (int ks = 0; ks < KP; ks += 32) {
    bf16x8 a0 = *(const bf16x8*)(a0p + ks);
    bf16x8 a1 = *(const bf16x8*)(a1p + ks);
    #pragma unroll
    for (int t = 0; t < 13; ++t) {
      bf16x8 b = *(const bf16x8*)(bp + (size_t)t * 16 * KP + ks);
      acc[0][t] = __builtin_amdgcn_mfma_f32_16x16x32_bf16(a0, b, acc[0][t], 0, 0, 0);
      acc[1][t] = __builtin_amdgcn_mfma_f32_16x16x32_bf16(a1, b, acc[1][t], 0, 0, 0);
    }
  }
  int rg = (lane >> 4) * 4;
  #pragma unroll
  for (int rt = 0; rt < 2; ++rt) {
    int row0 = rb + rt * 16 + rg;
    #pragma unroll
    for (int t = 0; t < 13; ++t) {
      int col = t * 16 + rl;
      if (col < 200) {
        #pragma unroll
        for (int g = 0; g < 4; ++g) {
          int row = row0 + g;
          if (row < M) C[(size_t)row * ldc + col] = acc[rt][t][g];
        }
      }
    }
  }
}

// ---------------- weight conversion to bf16 k-major padded ----------------
__global__ __launch_bounds__(256) void convB1(const float* __restrict__ ah, int koff,
                                              unsigned short* __restrict__ dst) {
  int idx = blockIdx.x * 256 + threadIdx.x;
  if (idx >= 208 * 128) return;
  int j = idx >> 7, k = idx & 127;
  float v = 0.f;
  if (j < 200 && k < 100) {
    const float* s = ah + ((j < 100) ? 0 : 30000) + (j % 100) * 300 + koff;
    v = s[k];
  }
  dst[idx] = bf16rne(v);
}

__global__ __launch_bounds__(256) void convBg(const float* __restrict__ src, int wsj, int wsk,
                                              int rows, int K, int Kp,
                                              unsigned short* __restrict__ dst) {
  int idx = blockIdx.x * 256 + threadIdx.x;
  if (idx >= 208 * Kp) return;
  int j = idx / Kp, k = idx - j * Kp;
  float v = (j < rows && k < K) ? src[(size_t)j * wsj + (size_t)k * wsk] : 0.f;
  dst[idx] = bf16rne(v);
}

// ---------------- f32 GEMM (small, rel matrices) ----------------
__global__ __launch_bounds__(256) void gemm2_f32(const float* __restrict__ A, int M, int Kd, int lda,
                                                 const float* __restrict__ W, int wsj, int wsk,
                                                 float* __restrict__ C, int ldc, int Ncols, int col0) {
  __shared__ float As[16][132];
  __shared__ float Bs[16][68];
  int tid = threadIdx.x;
  int tx = tid & 15, ty = tid >> 4;
  int row0 = blockIdx.y * 128;
  int colb = blockIdx.x * 64;
  float acc[8][4];
  #pragma unroll
  for (int i = 0; i < 8; ++i)
    #pragma unroll
    for (int j = 0; j < 4; ++j) acc[i][j] = 0.f;
  for (int kt = 0; kt < Kd; kt += 16) {
    #pragma unroll
    for (int l = 0; l < 8; ++l) {
      int idx = tid + l * 256;
      int m = idx >> 4, k = idx & 15;
      int gm = row0 + m, gk = kt + k;
      As[k][m] = (gm < M && gk < Kd) ? A[(size_t)gm * lda + gk] : 0.f;
    }
    #pragma unroll
    for (int l = 0; l < 4; ++l) {
      int idx = tid + l * 256;
      int j = idx >> 4, k = idx & 15;
      int gj = colb + j, gk = kt + k;
      Bs[k][j] = (gj < Ncols && gk < Kd) ? W[(size_t)gj * wsj + (size_t)gk * wsk] : 0.f;
    }
    __syncthreads();
    #pragma unroll
    for (int k = 0; k < 16; ++k) {
      float4 bv = *(const float4*)&Bs[k][tx * 4];
      float4 a0 = *(const float4*)&As[k][ty * 8];
      float4 a1 = *(const float4*)&As[k][ty * 8 + 4];
      float av[8] = {a0.x, a0.y, a0.z, a0.w, a1.x, a1.y, a1.z, a1.w};
      float bb[4] = {bv.x, bv.y, bv.z, bv.w};
      #pragma unroll
      for (int i = 0; i < 8; ++i)
        #pragma unroll
        for (int j = 0; j < 4; ++j)
          acc[i][j] += av[i] * bb[j];
    }
    __syncthreads();
  }
  int gj0 = colb + tx * 4;
  #pragma unroll
  for (int i = 0; i < 8; ++i) {
    int gm = row0 + ty * 8 + i;
    if (gm >= M) continue;
    float* cp = C + (size_t)gm * ldc + col0;
    #pragma unroll
    for (int j = 0; j < 4; ++j) if (gj0 + j < Ncols) cp[gj0 + j] = acc[i][j];
  }
}

// ---------------- per-row dots ----------------
__global__ __launch_bounds__(256) void dot2h(const float* __restrict__ P, const float* __restrict__ a2,
                                             float* __restrict__ outp, int M) {
  int row  = blockIdx.x * 4 + (threadIdx.x >> 6);
  int lane = threadIdx.x & 63;
  if (row >= M) return;
  const float* pr = P + (size_t)row * 200;
  float s0 = 0.f, s1 = 0.f;
  for (int k = lane; k < 100; k += 64) {
    s0 += pr[k] * a2[k];
    s1 += pr[100 + k] * a2[100 + k];
  }
  #pragma unroll
  for (int off = 1; off < 64; off <<= 1) { s0 += __shfl_xor(s0, off); s1 += __shfl_xor(s1, off); }
  if (lane == 0) { outp[row * 2] = s0; outp[row * 2 + 1] = s1; }
}

__global__ __launch_bounds__(256) void dot1(const float* __restrict__ P, const float* __restrict__ a2,
                                            float* __restrict__ outp, int M) {
  int row  = blockIdx.x * 4 + (threadIdx.x >> 6);
  int lane = threadIdx.x & 63;
  if (row >= M) return;
  const float* pr = P + (size_t)row * 200;
  float s = 0.f;
  for (int k = lane; k < 200; k += 64) s += pr[k] * a2[k];
  #pragma unroll
  for (int off = 1; off < 64; off <<= 1) s += __shfl_xor(s, off);
  if (lane == 0) outp[row] = s;
}

// ---------------- CSR build ----------------
__global__ __launch_bounds__(256) void histk(const int* __restrict__ el, const int* __restrict__ tin,
                                             int* __restrict__ deg) {
  int i = blockIdx.x * 256 + threadIdx.x;
  if (i >= ETOT) return;
  int e0 = (i < NEDGE) ? el[i] : tin[(size_t)(i - NEDGE) * 4 + 3];
  atomicAdd(&deg[e0], 1);
}

__global__ __launch_bounds__(256) void scanA(const int* __restrict__ deg, int* __restrict__ bsum, int n) {
  __shared__ int s[256];
  int t = threadIdx.x;
  int i = blockIdx.x * 256 + t;
  s[t] = (i < n) ? deg[i] : 0;
  __syncthreads();
  for (int off = 128; off > 0; off >>= 1) {
    if (t < off) s[t] += s[t + off];
    __syncthreads();
  }
  if (t == 0) bsum[blockIdx.x] = s[0];
}

__global__ __launch_bounds__(256) void scanB(int* __restrict__ bsum, int nb) {
  __shared__ int s[256];
  int t = threadIdx.x;
  int v = (t < nb) ? bsum[t] : 0;
  s[t] = v;
  __syncthreads();
  for (int off = 1; off < 256; off <<= 1) {
    int add = (t >= off) ? s[t - off] : 0;
    __syncthreads();
    s[t] += add;
    __syncthreads();
  }
  if (t < nb) bsum[t] = s[t] - v;  // exclusive
}

__global__ __launch_bounds__(256) void scanC(const int* __restrict__ deg, const int* __restrict__ bsum,
                                             int* __restrict__ offs, int* __restrict__ pos, int n, int total) {
  __shared__ int s[256];
  int t = threadIdx.x;
  int i = blockIdx.x * 256 + t;
  int v = (i < n) ? deg[i] : 0;
  s[t] = v;
  __syncthreads();
  for (int off = 1; off < 256; off <<= 1) {
    int add = (t >= off) ? s[t - off] : 0;
    __syncthreads();
    s[t] += add;
    __syncthreads();
  }
  if (i < n) {
    int e = bsum[blockIdx.x] + s[t] - v;
    offs[i] = e;
    pos[i]  = e;
  }
  if (i == 0) offs[n] = total;
}

__global__ __launch_bounds__(256) void scatterk(const int* __restrict__ el, const int* __restrict__ et,
                                                const int* __restrict__ tin,
                                                int* __restrict__ pos, int2* __restrict__ edata) {
  int i = blockIdx.x * 256 + threadIdx.x;
  if (i >= ETOT) return;
  int e0, e1, t1, t2f;
  if (i < NEDGE) {
    e0 = el[i]; e1 = el[NEDGE + i]; t1 = et[i]; t2f = 0;
  } else {
    const int* q = tin + (size_t)(i - NEDGE) * 4;
    e0 = q[3]; e1 = q[0]; t1 = q[1]; t2f = q[2] + 1;
  }
  int slot = atomicAdd(&pos[e0], 1);
  edata[slot] = make_int2(e1 | (t1 << 16), t2f);
}

// wave-aggregated list append: 2 atomics per wave instead of 1 per thread
__global__ __launch_bounds__(256) void buildLists(const int* __restrict__ offs,
                                                  int* __restrict__ lightL, int* __restrict__ heavyL,
                                                  int* __restrict__ cnts) {
  int i = blockIdx.x * 256 + threadIdx.x;
  int lane = threadIdx.x & 63;
  bool valid = (i < NN);
  int d = valid ? (offs[i + 1] - offs[i]) : 0;
  bool heavy = valid && (d > 64);
  bool light = valid && (d <= 64);
  unsigned long long mh = __ballot(heavy);
  unsigned long long ml = __ballot(light);
  unsigned long long below = (1ULL << lane) - 1ULL;
  int bh = 0, bl = 0;
  if (lane == 0) {
    if (mh) bh = atomicAdd(&cnts[1], __popcll(mh));
    if (ml) bl = atomicAdd(&cnts[0], __popcll(ml));
  }
  bh = __shfl(bh, 0);
  bl = __shfl(bl, 0);
  if (heavy) heavyL[bh + __popcll(mh & below)] = i;
  if (light) lightL[bl + __popcll(ml & below)] = i;
}

// ---------------- layer-1 gather: light (wave/node) ----------------
__global__ __launch_bounds__(256) void gather1L(const int* __restrict__ lightL, const int* __restrict__ cnts,
    const int* __restrict__ offs, const int2* __restrict__ edata,
    const float* __restrict__ srcp, const float* __restrict__ dstp, const float* __restrict__ relp,
    const float* __restrict__ ssrc, const float* __restrict__ sdst, const float* __restrict__ srel,
    unsigned short* __restrict__ xbf) {
  int widx = blockIdx.x * 4 + (threadIdx.x >> 6);
  if (widx >= cnts[0]) return;
  int node = lightL[widx];
  int lane = threadIdx.x & 63;
  int s = offs[node], e = offs[node + 1];
  float s00 = ssrc[node * 2], s01 = ssrc[node * 2 + 1];
  int c0 = lane, c1 = lane + 64, c2 = lane + 128, c3 = lane + 192;
  float acc0 = 0.f, acc1 = 0.f, acc2 = 0.f, acc3 = 0.f, rs0 = 0.f, rs1 = 0.f;
  for (int q = s; q < e; ++q) {
    int2 ed = edata[q];
    unsigned w0 = (unsigned)ed.x;
    int e1 = (int)(w0 & 0xFFFFu);
    int t1 = (int)(w0 >> 16);
    int t2f = ed.y;
    float p0 = s00 + sdst[e1 * 2]     + srel[t1 * 2];
    float p1 = s01 + sdst[e1 * 2 + 1] + srel[t1 * 2 + 1];
    const float* rd = dstp + (size_t)e1 * 200;
    const float* r1 = relp + t1 * 200;
    float m0, m1, m2, m3;
    if (t2f) {
      int t2 = t2f - 1;
      p0 += srel[t2 * 2]; p1 += srel[t2 * 2 + 1];
      const float* r2 = relp + t2 * 200;
      m0 = rd[c0] + r1[c0] + r2[c0];
      m1 = rd[c1] + r1[c1] + r2[c1];
      m2 = rd[c2] + r1[c2] + r2[c2];
      m3 = (c3 < 200) ? rd[c3] + r1[c3] + r2[c3] : 0.f;
    } else {
      m0 = rd[c0] + r1[c0];
      m1 = rd[c1] + r1[c1];
      m2 = rd[c2] + r1[c2];
      m3 = (c3 < 200) ? rd[c3] + r1[c3] : 0.f;
    }
    p0 = (p0 > 0.f) ? p0 : 0.2f * p0;
    p1 = (p1 > 0.f) ? p1 : 0.2f * p1;
    float ee0 = __expf(-p0), ee1 = __expf(-p1);
    rs0 += ee0; rs1 += ee1;
    acc0 += ee0 * m0;
    acc1 += ((c1 < 100) ? ee0 : ee1) * m1;
    acc2 += ee1 * m2;
    acc3 += ee1 * m3;
  }
  bool has = (e > s);
  float inv0 = has ? 1.f / rs0 : 0.f;
  float inv1 = has ? 1.f / rs1 : 0.f;
  const float* sp = srcp + (size_t)node * 200;
  unsigned short* xo = xbf + (size_t)node * 224;
  float v;
  v = has ? sp[c0] + acc0 * inv0 : 0.f;                       v = (v > 0.f) ? v : expm1f(v); xo[c0] = bf16rne(v);
  v = has ? sp[c1] + acc1 * ((c1 < 100) ? inv0 : inv1) : 0.f; v = (v > 0.f) ? v : expm1f(v); xo[c1] = bf16rne(v);
  v = has ? sp[c2] + acc2 * inv1 : 0.f;                       v = (v > 0.f) ? v : expm1f(v); xo[c2] = bf16rne(v);
  if (c3 < 200) {
    v = has ? sp[c3] + acc3 * inv1 : 0.f;
    v = (v > 0.f) ? v : expm1f(v);
    xo[c3] = bf16rne(v);
  } else if (c3 < 224) {
    xo[c3] = 0;
  }
}

// ---------------- layer-1 gather: heavy (block/node, 8 waves) ----------------
__global__ __launch_bounds__(512) void gather1H(const int* __restrict__ heavyL, const int* __restrict__ cnts,
    const int* __restrict__ offs, const int2* __restrict__ edata,
    const float* __restrict__ srcp, const float* __restrict__ dstp, const float* __restrict__ relp,
    const float* __restrict__ ssrc, const float* __restrict__ sdst, const float* __restrict__ srel,
    unsigned short* __restrict__ xbf) {
  __shared__ float part[8][208];
  if (blockIdx.x >= (unsigned)cnts[1]) return;
  int node = heavyL[blockIdx.x];
  int w = threadIdx.x >> 6, lane = threadIdx.x & 63;
  int s = offs[node], e = offs[node + 1];
  float s00 = ssrc[node * 2], s01 = ssrc[node * 2 + 1];
  int c0 = lane, c1 = lane + 64, c2 = lane + 128, c3 = lane + 192;
  float acc0 = 0.f, acc1 = 0.f, acc2 = 0.f, acc3 = 0.f, rs0 = 0.f, rs1 = 0.f;
  for (int q = s + w; q < e; q += 8) {
    int2 ed = edata[q];
    unsigned w0 = (unsigned)ed.x;
    int e1 = (int)(w0 & 0xFFFFu);
    int t1 = (int)(w0 >> 16);
    int t2f = ed.y;
    float p0 = s00 + sdst[e1 * 2]     + srel[t1 * 2];
    float p1 = s01 + sdst[e1 * 2 + 1] + srel[t1 * 2 + 1];
    const float* rd = dstp + (size_t)e1 * 200;
    const float* r1 = relp + t1 * 200;
    float m0, m1, m2, m3;
    if (t2f) {
      int t2 = t2f - 1;
      p0 += srel[t2 * 2]; p1 += srel[t2 * 2 + 1];
      const float* r2 = relp + t2 * 200;
      m0 = rd[c0] + r1[c0] + r2[c0];
      m1 = rd[c1] + r1[c1] + r2[c1];
      m2 = rd[c2] + r1[c2] + r2[c2];
      m3 = (c3 < 200) ? rd[c3] + r1[c3] + r2[c3] : 0.f;
    } else {
      m0 = rd[c0] + r1[c0];
      m1 = rd[c1] + r1[c1];
      m2 = rd[c2] + r1[c2];
      m3 = (c3 < 200) ? rd[c3] + r1[c3] : 0.f;
    }
    p0 = (p0 > 0.f) ? p0 : 0.2f * p0;
    p1 = (p1 > 0.f) ? p1 : 0.2f * p1;
    float ee0 = __expf(-p0), ee1 = __expf(-p1);
    rs0 += ee0; rs1 += ee1;
    acc0 += ee0 * m0;
    acc1 += ((c1 < 100) ? ee0 : ee1) * m1;
    acc2 += ee1 * m2;
    acc3 += ee1 * m3;
  }
  part[w][c0] = acc0; part[w][c1] = acc1; part[w][c2] = acc2;
  if (c3 < 200) part[w][c3] = acc3;
  if (lane == 0) { part[w][200] = rs0; part[w][201] = rs1; }
  __syncthreads();
  int t = threadIdx.x;
  if (t < 224) {
    unsigned short outv = 0;
    if (t < 200) {
      float a = 0.f, r0 = 0.f, r1 = 0.f;
      #pragma unroll
      for (int wv = 0; wv < 8; ++wv) { a += part[wv][t]; r0 += part[wv][200]; r1 += part[wv][201]; }
      float inv = (t < 100) ? 1.f / r0 : 1.f / r1;
      float v = srcp[(size_t)node * 200 + t] + a * inv;
      v = (v > 0.f) ? v : expm1f(v);
      outv = bf16rne(v);
    }
    xbf[(size_t)node * 224 + t] = outv;
  }
}

// ---------------- layer-2 gather: light ----------------
__global__ __launch_bounds__(256) void gather2L(const int* __restrict__ lightL, const int* __restrict__ cnts,
    const int* __restrict__ offs, const int2* __restrict__ edata,
    const float* __restrict__ srcp, const float* __restrict__ dstp, const float* __restrict__ relp,
    const float* __restrict__ ssrc, const float* __restrict__ sdst, const float* __restrict__ srel,
    float* __restrict__ hout) {
  int widx = blockIdx.x * 4 + (threadIdx.x >> 6);
  if (widx >= cnts[0]) return;
  int node = lightL[widx];
  int lane = threadIdx.x & 63;
  int s = offs[node], e = offs[node + 1];
  float s0 = ssrc[node];
  int c0 = lane, c1 = lane + 64, c2 = lane + 128, c3 = lane + 192;
  float acc0 = 0.f, acc1 = 0.f, acc2 = 0.f, acc3 = 0.f, rs = 0.f;
  for (int q = s; q < e; ++q) {
    int2 ed = edata[q];
    unsigned w0 = (unsigned)ed.x;
    int e1 = (int)(w0 & 0xFFFFu);
    int t1 = (int)(w0 >> 16);
    int t2f = ed.y;
    float p = s0 + sdst[e1] + srel[t1];
    const float* rd = dstp + (size_t)e1 * 200;
    const float* r1 = relp + t1 * 200;
    float m0, m1, m2, m3;
    if (t2f) {
      int t2 = t2f - 1;
      p += srel[t2];
      const float* r2 = relp + t2 * 200;
      m0 = rd[c0] + r1[c0] + r2[c0];
      m1 = rd[c1] + r1[c1] + r2[c1];
      m2 = rd[c2] + r1[c2] + r2[c2];
      m3 = (c3 < 200) ? rd[c3] + r1[c3] + r2[c3] : 0.f;
    } else {
      m0 = rd[c0] + r1[c0];
      m1 = rd[c1] + r1[c1];
      m2 = rd[c2] + r1[c2];
      m3 = (c3 < 200) ? rd[c3] + r1[c3] : 0.f;
    }
    p = (p > 0.f) ? p : 0.2f * p;
    float ee = __expf(-p);
    rs += ee;
    acc0 += ee * m0; acc1 += ee * m1; acc2 += ee * m2; acc3 += ee * m3;
  }
  bool has = (e > s);
  float inv = has ? 1.f / rs : 0.f;
  const float* sp = srcp + (size_t)node * 200;
  float* ho = hout + (size_t)node * 200;
  float v;
  v = has ? sp[c0] + acc0 * inv : 0.f; ho[c0] = (v > 0.f) ? v : expm1f(v);
  v = has ? sp[c1] + acc1 * inv : 0.f; ho[c1] = (v > 0.f) ? v : expm1f(v);
  v = has ? sp[c2] + acc2 * inv : 0.f; ho[c2] = (v > 0.f) ? v : expm1f(v);
  if (c3 < 200) {
    v = has ? sp[c3] + acc3 * inv : 0.f;
    ho[c3] = (v > 0.f) ? v : expm1f(v);
  }
}

// ---------------- layer-2 gather: heavy ----------------
__global__ __launch_bounds__(512) void gather2H(const int* __restrict__ heavyL, const int* __restrict__ cnts,
    const int* __restrict__ offs, const int2* __restrict__ edata,
    const float* __restrict__ srcp, const float* __restrict__ dstp, const float* __restrict__ relp,
    const float* __restrict__ ssrc, const float* __restrict__ sdst, const float* __restrict__ srel,
    float* __restrict__ hout) {
  __shared__ float part[8][208];
  if (blockIdx.x >= (unsigned)cnts[1]) return;
  int node = heavyL[blockIdx.x];
  int w = threadIdx.x >> 6, lane = threadIdx.x & 63;
  int s = offs[node], e = offs[node + 1];
  float s0 = ssrc[node];
  int c0 = lane, c1 = lane + 64, c2 = lane + 128, c3 = lane + 192;
  float acc0 = 0.f, acc1 = 0.f, acc2 = 0.f, acc3 = 0.f, rs = 0.f;
  for (int q = s + w; q < e; q += 8) {
    int2 ed = edata[q];
    unsigned w0 = (unsigned)ed.x;
    int e1 = (int)(w0 & 0xFFFFu);
    int t1 = (int)(w0 >> 16);
    int t2f = ed.y;
    float p = s0 + sdst[e1] + srel[t1];
    const float* rd = dstp + (size_t)e1 * 200;
    const float* r1 = relp + t1 * 200;
    float m0, m1, m2, m3;
    if (t2f) {
      int t2 = t2f - 1;
      p += srel[t2];
      const float* r2 = relp + t2 * 200;
      m0 = rd[c0] + r1[c0] + r2[c0];
      m1 = rd[c1] + r1[c1] + r2[c1];
      m2 = rd[c2] + r1[c2] + r2[c2];
      m3 = (c3 < 200) ? rd[c3] + r1[c3] + r2[c3] : 0.f;
    } else {
      m0 = rd[c0] + r1[c0];
      m1 = rd[c1] + r1[c1];
      m2 = rd[c2] + r1[c2];
      m3 = (c3 < 200) ? rd[c3] + r1[c3] : 0.f;
    }
    p = (p > 0.f) ? p : 0.2f * p;
    float ee = __expf(-p);
    rs += ee;
    acc0 += ee * m0; acc1 += ee * m1; acc2 += ee * m2; acc3 += ee * m3;
  }
  part[w][c0] = acc0; part[w][c1] = acc1; part[w][c2] = acc2;
  if (c3 < 200) part[w][c3] = acc3;
  if (lane == 0) part[w][200] = rs;
  __syncthreads();
  int t = threadIdx.x;
  if (t < 200) {
    float a = 0.f, r = 0.f;
    #pragma unroll
    for (int wv = 0; wv < 8; ++wv) { a += part[wv][t]; r += part[wv][200]; }
    float v = srcp[(size_t)node * 200 + t] + a / r;
    hout[(size_t)node * 200 + t] = (v > 0.f) ? v : expm1f(v);
  }
}

// ---------------- pad xbf rows [NN, MP) ----------------
__global__ __launch_bounds__(256) void padx(unsigned short* __restrict__ xbf) {
  int i = blockIdx.x * 256 + threadIdx.x;
  if (i < (MP - NN) * 224) xbf[(size_t)NN * 224 + i] = 0;
}

// ---------------- mask scatter ----------------
__global__ __launch_bounds__(256) void maskset(const int* __restrict__ bi, float* __restrict__ maskA) {
  int t = blockIdx.x * 256 + threadIdx.x;
  if (t < BATCH) maskA[bi[t * 3 + 2]] = 1.0f;
}

// ---------------- final: out = l2norm(xw + mask*h2), in place on d_out ----------------
__global__ __launch_bounds__(256) void finalk2(const float* __restrict__ xw, const float* __restrict__ h2,
                                               const float* __restrict__ maskA, float* __restrict__ out) {
  int row  = blockIdx.x * 4 + (threadIdx.x >> 6);
  int lane = threadIdx.x & 63;
  if (row >= NN) return;
  float m = maskA[row];
  const float* xr = xw + (size_t)row * 200;
  const float* hr = h2 + (size_t)row * 200;
  int c0 = lane, c1 = lane + 64, c2 = lane + 128, c3 = lane + 192;
  float v0 = xr[c0] + m * hr[c0];
  float v1 = xr[c1] + m * hr[c1];
  float v2 = xr[c2] + m * hr[c2];
  float v3 = (c3 < 200) ? xr[c3] + m * hr[c3] : 0.f;
  float ss = v0 * v0 + v1 * v1 + v2 * v2 + v3 * v3;
  #pragma unroll
  for (int off = 1; off < 64; off <<= 1) ss += __shfl_xor(ss, off);
  float inv = 1.f / fmaxf(sqrtf(ss), 1e-12f);
  float* o = out + (size_t)row * 200;
  o[c0] = v0 * inv; o[c1] = v1 * inv; o[c2] = v2 * inv;
  if (c3 < 200) o[c3] = v3 * inv;
}

extern "C" void kernel_launch(void* const* d_in, const int* in_sizes, int n_in,
                              void* d_out, int out_size, void* d_ws, size_t ws_size,
                              hipStream_t stream) {
  (void)in_sizes; (void)n_in; (void)out_size; (void)ws_size;
  const float* ent      = (const float*)d_in[0];
  const float* rel      = (const float*)d_in[1];
  const float* a_heads  = (const float*)d_in[3];
  const float* a2_heads = (const float*)d_in[4];
  const float* W_gat    = (const float*)d_in[5];
  const float* a_out    = (const float*)d_in[6];
  const float* a2_out   = (const float*)d_in[7];
  const float* W_ent    = (const float*)d_in[8];
  const int* edge_list  = (const int*)d_in[9];
  const int* edge_type  = (const int*)d_in[10];
  const int* tin        = (const int*)d_in[11];
  const int* binp       = (const int*)d_in[12];

  float* out    = (float*)d_out;
  float* outrel = out + 10000000;     // (500,200)

  float* ws    = (float*)d_ws;
  float* bufS  = ws;                  // 10M: srcp1 -> srcp2 -> h2 (in place)
  float* bufD  = ws + 10000000;       // 10M: dstp1 -> dstp2
  float* relp1 = ws + 20000000;       // 100k
  float* relp2 = ws + 20100000;       // 100k
  float* ssrc1 = ws + 20200000;       // 100k (N*2)
  float* sdst1 = ws + 20300000;       // 100k
  float* s2src = ws + 20400000;       // 50k
  float* s2dst = ws + 20450000;       // 50k
  float* srel1 = ws + 20500000;       // 1000
  float* s2rel = ws + 20501000;       // 500
  float* maskA = ws + 20502000;       // 50k
  unsigned short* x0nbf = (unsigned short*)(ws + 20560000); // MP*128 bf16
  unsigned short* xbf   = (unsigned short*)(ws + 23800000); // MP*224 bf16
  unsigned short* B1s   = (unsigned short*)(ws + 29500000); // 208*128
  unsigned short* B1d   = (unsigned short*)(ws + 29520000);
  unsigned short* Bxw   = (unsigned short*)(ws + 29540000);
  unsigned short* B2s   = (unsigned short*)(ws + 29560000); // 208*224
  unsigned short* B2d   = (unsigned short*)(ws + 29590000);
  int* ibase  = (int*)(ws + 29700000);
  int* deg    = ibase;                // 50k
  int* offs   = ibase + 50000;        // 50k+1
  int* pos    = ibase + 100016;       // 50k
  int* bsum   = ibase + 150016;       // 256
  int* cnts   = ibase + 150272;       // 2
  int* lightL = ibase + 150280;       // 50k
  int* heavyL = ibase + 200280;       // 50k
  int2* edata = (int2*)(ibase + 250288); // 375k int2

  hipMemsetAsync(deg,   0, (size_t)NN * 4, stream);
  hipMemsetAsync(maskA, 0, (size_t)NN * 4, stream);
  hipMemsetAsync(cnts,  0, 8, stream);

  l2norm_bf16<<<12512, 256, 0, stream>>>(ent, x0nbf);

  // CSR + lists
  histk<<<(ETOT + 255) / 256, 256, 0, stream>>>(edge_list, tin, deg);
  scanA<<<196, 256, 0, stream>>>(deg, bsum, NN);
  scanB<<<1, 256, 0, stream>>>(bsum, 196);
  scanC<<<196, 256, 0, stream>>>(deg, bsum, offs, pos, NN, ETOT);
  scatterk<<<(ETOT + 255) / 256, 256, 0, stream>>>(edge_list, edge_type, tin, pos, edata);
  buildLists<<<196, 256, 0, stream>>>(offs, lightL, heavyL, cnts);

  // weight conversion
  convB1<<<104, 256, 0, stream>>>(a_heads, 0,   B1s);
  convB1<<<104, 256, 0, stream>>>(a_heads, 100, B1d);
  convBg<<<104, 256, 0, stream>>>(W_ent, 1, 200, 200, 100, 128, Bxw);
  convBg<<<182, 256, 0, stream>>>(a_out,       600, 1, 200, 200, 224, B2s);
  convBg<<<182, 256, 0, stream>>>(a_out + 200, 600, 1, 200, 200, 224, B2d);

  // layer-1 projections + xw (bf16 MFMA)
  gemm_bf16<128><<<391, 256, 0, stream>>>(x0nbf, B1s, bufS, NN, 200);
  gemm_bf16<128><<<391, 256, 0, stream>>>(x0nbf, B1d, bufD, NN, 200);
  gemm_bf16<128><<<391, 256, 0, stream>>>(x0nbf, Bxw, out,  NN, 200);

  // rel projections (f32, small)
  dim3 g2(2, 4);
  gemm2_f32<<<g2, 256, 0, stream>>>(rel, NRELS, 100, 100, a_heads + 200,         300, 1, relp1, 200, 100, 0);
  gemm2_f32<<<g2, 256, 0, stream>>>(rel, NRELS, 100, 100, a_heads + 30000 + 200, 300, 1, relp1, 200, 100, 100);

  dot2h<<<12500, 256, 0, stream>>>(bufS, a2_heads, ssrc1, NN);
  dot2h<<<12500, 256, 0, stream>>>(bufD, a2_heads, sdst1, NN);
  dot2h<<<125,   256, 0, stream>>>(relp1, a2_heads, srel1, NRELS);

  gather1L<<<12500, 256, 0, stream>>>(lightL, cnts, offs, edata, bufS, bufD, relp1, ssrc1, sdst1, srel1, xbf);
  gather1H<<<5792, 512, 0, stream>>>(heavyL, cnts, offs, edata, bufS, bufD, relp1, ssrc1, sdst1, srel1, xbf);
  padx<<<42, 256, 0, stream>>>(xbf);

  // layer-2 projections (bf16 MFMA, overwrite bufS/bufD)
  gemm_bf16<224><<<391, 256, 0, stream>>>(xbf, B2s, bufS, NN, 200);
  gemm_bf16<224><<<391, 256, 0, stream>>>(xbf, B2d, bufD, NN, 200);

  // out_relation_1 and relp2 (f32, small)
  dim3 g3(4, 4);
  gemm2_f32<<<g3, 256, 0, stream>>>(rel, NRELS, 100, 100, W_gat, 1, 200, outrel, 200, 200, 0);
  gemm2_f32<<<g3, 256, 0, stream>>>(outrel, NRELS, 200, 200, a_out + 400, 600, 1, relp2, 200, 200, 0);

  dot1<<<12500, 256, 0, stream>>>(bufS, a2_out, s2src, NN);
  dot1<<<12500, 256, 0, stream>>>(bufD, a2_out, s2dst, NN);
  dot1<<<125,   256, 0, stream>>>(relp2, a2_out, s2rel, NRELS);

  maskset<<<256, 256, 0, stream>>>(binp, maskA);

  gather2L<<<12500, 256, 0, stream>>>(lightL, cnts, offs, edata, bufS, bufD, relp2, s2src, s2dst, s2rel, bufS);
  gather2H<<<5792, 512, 0, stream>>>(heavyL, cnts, offs, edata, bufS, bufD, relp2, s2src, s2dst, s2rel, bufS);

  finalk2<<<12500, 256, 0, stream>>>(out, bufS, maskA, out);
}

// Round 6
// 652.531 us; speedup vs baseline: 1.9450x; 1.0785x over previous
//
#include <hip/hip_runtime.h>
#include <math.h>

#define NN    50000
#define MP    50048    // padded rows (391*128)
#define NEDGE 250000
#define NHOPE 125000
#define ETOT  375000
#define NRELS 500
#define BATCH 65536
#define LB1   6250     // light blocks in merged gather (8 waves each -> 50000 waves)
#define HBMAX 5769     // max heavy nodes (deg>64): 375000/65

typedef __attribute__((ext_vector_type(8))) short bf16x8;
typedef __attribute__((ext_vector_type(4))) float f32x4;

__device__ __forceinline__ unsigned short bf16rne(float f) {
  unsigned u = __float_as_uint(f);
  unsigned r = (u + 0x7FFFu + ((u >> 16) & 1u)) >> 16;
  return (unsigned short)r;
}
__device__ __forceinline__ float b2f(unsigned short u) {
  return __uint_as_float(((unsigned)u) << 16);
}

struct GJob {
  const unsigned short* B;   // 208 x KP bf16
  float* Cf;                 // f32 out (ld 200) or null
  unsigned short* Cbf;       // bf16 out (ld 200) or null
  const float* a2;           // 200 floats or null
  float* dot;                // per-row scalar(s) or null
  int dotmode;               // 1 = split at 100 (two heads), 2 = single sum
};

// ---------------- l2norm -> bf16 padded (MP x 128) ----------------
__global__ __launch_bounds__(256) void l2norm_bf16(const float* __restrict__ in,
                                                   unsigned short* __restrict__ out) {
  int row  = blockIdx.x * 4 + (threadIdx.x >> 6);
  int lane = threadIdx.x & 63;
  if (row >= MP) return;
  unsigned short* o = out + (size_t)row * 128;
  if (row >= NN) { o[lane] = 0; o[lane + 64] = 0; return; }
  const float* r = in + (size_t)row * 100;
  float v0 = r[lane];
  float v1 = (lane + 64 < 100) ? r[lane + 64] : 0.f;
  float ss = v0 * v0 + v1 * v1;
  #pragma unroll
  for (int off = 1; off < 64; off <<= 1) ss += __shfl_xor(ss, off);
  float inv = 1.f / fmaxf(sqrtf(ss), 1e-12f);
  o[lane] = bf16rne(v0 * inv);
  o[lane + 64] = (lane + 64 < 100) ? bf16rne(v1 * inv) : (unsigned short)0;
}

// ---------------- multi-job bf16 MFMA GEMM with fused epilogue ----------------
template<int KP>
__global__ __launch_bounds__(256) void gemm_multi(const unsigned short* __restrict__ A,
                                                  GJob j0, GJob j1, GJob j2, int M) {
  GJob jb = (blockIdx.y == 0) ? j0 : ((blockIdx.y == 1) ? j1 : j2);
  int wave = threadIdx.x >> 6, lane = threadIdx.x & 63;
  int rb = blockIdx.x * 128 + wave * 32;
  int rl = lane & 15;
  int kq = (lane >> 4) * 8;
  const unsigned short* a0p = A + (size_t)(rb + rl) * KP + kq;
  const unsigned short* a1p = a0p + (size_t)16 * KP;
  const unsigned short* bp  = jb.B + (size_t)rl * KP + kq;
  f32x4 acc[2][13];
  #pragma unroll
  for (int i = 0; i < 2; ++i)
    #pragma unroll
    for (int t = 0; t < 13; ++t) acc[i][t] = (f32x4){0.f, 0.f, 0.f, 0.f};
  #pragma unroll 2
  for (int ks = 0; ks < KP; ks += 32) {
    bf16x8 a0 = *(const bf16x8*)(a0p + ks);
    bf16x8 a1 = *(const bf16x8*)(a1p + ks);
    #pragma unroll
    for (int t = 0; t < 13; ++t) {
      bf16x8 b = *(const bf16x8*)(bp + (size_t)t * 16 * KP + ks);
      acc[0][t] = __builtin_amdgcn_mfma_f32_16x16x32_bf16(a0, b, acc[0][t], 0, 0, 0);
      acc[1][t] = __builtin_amdgcn_mfma_f32_16x16x32_bf16(a1, b, acc[1][t], 0, 0, 0);
    }
  }
  int rg = (lane >> 4) * 4;
  if (jb.Cf) {
    #pragma unroll
    for (int rt = 0; rt < 2; ++rt) {
      int row0 = rb + rt * 16 + rg;
      #pragma unroll
      for (int t = 0; t < 13; ++t) {
        int col = t * 16 + rl;
        if (col < 200) {
          #pragma unroll
          for (int g = 0; g < 4; ++g) {
            int row = row0 + g;
            if (row < M) jb.Cf[(size_t)row * 200 + col] = acc[rt][t][g];
          }
        }
      }
    }
  }
  if (jb.Cbf) {
    #pragma unroll
    for (int rt = 0; rt < 2; ++rt) {
      int row0 = rb + rt * 16 + rg;
      #pragma unroll
      for (int t = 0; t < 13; ++t) {
        int col = t * 16 + rl;
        if (col < 200) {
          #pragma unroll
          for (int g = 0; g < 4; ++g) {
            int row = row0 + g;
            if (row < M) jb.Cbf[(size_t)row * 200 + col] = bf16rne(acc[rt][t][g]);
          }
        }
      }
    }
  }
  if (jb.dot) {
    #pragma unroll
    for (int rt = 0; rt < 2; ++rt) {
      float p0[4] = {0.f, 0.f, 0.f, 0.f}, p1[4] = {0.f, 0.f, 0.f, 0.f};
      #pragma unroll
      for (int t = 0; t < 13; ++t) {
        int col = t * 16 + rl;
        float av = (col < 200) ? jb.a2[col] : 0.f;
        bool lo = (col < 100);
        #pragma unroll
        for (int g = 0; g < 4; ++g) {
          float v = acc[rt][t][g] * av;
          if (lo) p0[g] += v; else p1[g] += v;
        }
      }
      #pragma unroll
      for (int off = 1; off < 16; off <<= 1) {
        #pragma unroll
        for (int g = 0; g < 4; ++g) {
          p0[g] += __shfl_xor(p0[g], off);
          p1[g] += __shfl_xor(p1[g], off);
        }
      }
      if (rl == 0) {
        int row0 = rb + rt * 16 + rg;
        #pragma unroll
        for (int g = 0; g < 4; ++g) {
          int row = row0 + g;
          if (row < M) {
            if (jb.dotmode == 1) { jb.dot[row * 2] = p0[g]; jb.dot[row * 2 + 1] = p1[g]; }
            else                 { jb.dot[row] = p0[g] + p1[g]; }
          }
        }
      }
    }
  }
}

// ---------------- weight conversion to bf16 k-major padded ----------------
__global__ __launch_bounds__(256) void convB1(const float* __restrict__ ah, int koff,
                                              unsigned short* __restrict__ dst) {
  int idx = blockIdx.x * 256 + threadIdx.x;
  if (idx >= 208 * 128) return;
  int j = idx >> 7, k = idx & 127;
  float v = 0.f;
  if (j < 200 && k < 100) {
    const float* s = ah + ((j < 100) ? 0 : 30000) + (j % 100) * 300 + koff;
    v = s[k];
  }
  dst[idx] = bf16rne(v);
}

__global__ __launch_bounds__(256) void convBg(const float* __restrict__ src, int wsj, int wsk,
                                              int rows, int K, int Kp,
                                              unsigned short* __restrict__ dst) {
  int idx = blockIdx.x * 256 + threadIdx.x;
  if (idx >= 208 * Kp) return;
  int j = idx / Kp, k = idx - j * Kp;
  float v = (j < rows && k < K) ? src[(size_t)j * wsj + (size_t)k * wsk] : 0.f;
  dst[idx] = bf16rne(v);
}

// ---------------- f32 GEMM (small, rel matrices) ----------------
__global__ __launch_bounds__(256) void gemm2_f32(const float* __restrict__ A, int M, int Kd, int lda,
                                                 const float* __restrict__ W, int wsj, int wsk,
                                                 float* __restrict__ C, int ldc, int Ncols, int col0) {
  __shared__ float As[16][132];
  __shared__ float Bs[16][68];
  int tid = threadIdx.x;
  int tx = tid & 15, ty = tid >> 4;
  int row0 = blockIdx.y * 128;
  int colb = blockIdx.x * 64;
  float acc[8][4];
  #pragma unroll
  for (int i = 0; i < 8; ++i)
    #pragma unroll
    for (int j = 0; j < 4; ++j) acc[i][j] = 0.f;
  for (int kt = 0; kt < Kd; kt += 16) {
    #pragma unroll
    for (int l = 0; l < 8; ++l) {
      int idx = tid + l * 256;
      int m = idx >> 4, k = idx & 15;
      int gm = row0 + m, gk = kt + k;
      As[k][m] = (gm < M && gk < Kd) ? A[(size_t)gm * lda + gk] : 0.f;
    }
    #pragma unroll
    for (int l = 0; l < 4; ++l) {
      int idx = tid + l * 256;
      int j = idx >> 4, k = idx & 15;
      int gj = colb + j, gk = kt + k;
      Bs[k][j] = (gj < Ncols && gk < Kd) ? W[(size_t)gj * wsj + (size_t)gk * wsk] : 0.f;
    }
    __syncthreads();
    #pragma unroll
    for (int k = 0; k < 16; ++k) {
      float4 bv = *(const float4*)&Bs[k][tx * 4];
      float4 a0 = *(const float4*)&As[k][ty * 8];
      float4 a1 = *(const float4*)&As[k][ty * 8 + 4];
      float av[8] = {a0.x, a0.y, a0.z, a0.w, a1.x, a1.y, a1.z, a1.w};
      float bb[4] = {bv.x, bv.y, bv.z, bv.w};
      #pragma unroll
      for (int i = 0; i < 8; ++i)
        #pragma unroll
        for (int j = 0; j < 4; ++j)
          acc[i][j] += av[i] * bb[j];
    }
    __syncthreads();
  }
  int gj0 = colb + tx * 4;
  #pragma unroll
  for (int i = 0; i < 8; ++i) {
    int gm = row0 + ty * 8 + i;
    if (gm >= M) continue;
    float* cp = C + (size_t)gm * ldc + col0;
    #pragma unroll
    for (int j = 0; j < 4; ++j) if (gj0 + j < Ncols) cp[gj0 + j] = acc[i][j];
  }
}

// ---------------- per-row dots (rel rows only) ----------------
__global__ __launch_bounds__(256) void dot2h(const float* __restrict__ P, const float* __restrict__ a2,
                                             float* __restrict__ outp, int M) {
  int row  = blockIdx.x * 4 + (threadIdx.x >> 6);
  int lane = threadIdx.x & 63;
  if (row >= M) return;
  const float* pr = P + (size_t)row * 200;
  float s0 = 0.f, s1 = 0.f;
  for (int k = lane; k < 100; k += 64) {
    s0 += pr[k] * a2[k];
    s1 += pr[100 + k] * a2[100 + k];
  }
  #pragma unroll
  for (int off = 1; off < 64; off <<= 1) { s0 += __shfl_xor(s0, off); s1 += __shfl_xor(s1, off); }
  if (lane == 0) { outp[row * 2] = s0; outp[row * 2 + 1] = s1; }
}

__global__ __launch_bounds__(256) void dot1(const float* __restrict__ P, const float* __restrict__ a2,
                                            float* __restrict__ outp, int M) {
  int row  = blockIdx.x * 4 + (threadIdx.x >> 6);
  int lane = threadIdx.x & 63;
  if (row >= M) return;
  const float* pr = P + (size_t)row * 200;
  float s = 0.f;
  for (int k = lane; k < 200; k += 64) s += pr[k] * a2[k];
  #pragma unroll
  for (int off = 1; off < 64; off <<= 1) s += __shfl_xor(s, off);
  if (lane == 0) outp[row] = s;
}

// ---------------- CSR build ----------------
__global__ __launch_bounds__(256) void histk(const int* __restrict__ el, const int* __restrict__ tin,
                                             int* __restrict__ deg) {
  int i = blockIdx.x * 256 + threadIdx.x;
  if (i >= ETOT) return;
  int e0 = (i < NEDGE) ? el[i] : tin[(size_t)(i - NEDGE) * 4 + 3];
  atomicAdd(&deg[e0], 1);
}

__global__ __launch_bounds__(256) void scanA(const int* __restrict__ deg, int* __restrict__ bsum, int n) {
  __shared__ int s[256];
  int t = threadIdx.x;
  int i = blockIdx.x * 256 + t;
  s[t] = (i < n) ? deg[i] : 0;
  __syncthreads();
  for (int off = 128; off > 0; off >>= 1) {
    if (t < off) s[t] += s[t + off];
    __syncthreads();
  }
  if (t == 0) bsum[blockIdx.x] = s[0];
}

__global__ __launch_bounds__(256) void scanB(int* __restrict__ bsum, int nb) {
  __shared__ int s[256];
  int t = threadIdx.x;
  int v = (t < nb) ? bsum[t] : 0;
  s[t] = v;
  __syncthreads();
  for (int off = 1; off < 256; off <<= 1) {
    int add = (t >= off) ? s[t - off] : 0;
    __syncthreads();
    s[t] += add;
    __syncthreads();
  }
  if (t < nb) bsum[t] = s[t] - v;  // exclusive
}

__global__ __launch_bounds__(256) void scanC(const int* __restrict__ deg, const int* __restrict__ bsum,
                                             int* __restrict__ offs, int* __restrict__ pos, int n, int total) {
  __shared__ int s[256];
  int t = threadIdx.x;
  int i = blockIdx.x * 256 + t;
  int v = (i < n) ? deg[i] : 0;
  s[t] = v;
  __syncthreads();
  for (int off = 1; off < 256; off <<= 1) {
    int add = (t >= off) ? s[t - off] : 0;
    __syncthreads();
    s[t] += add;
    __syncthreads();
  }
  if (i < n) {
    int e = bsum[blockIdx.x] + s[t] - v;
    offs[i] = e;
    pos[i]  = e;
  }
  if (i == 0) offs[n] = total;
}

__global__ __launch_bounds__(256) void scatterk(const int* __restrict__ el, const int* __restrict__ et,
                                                const int* __restrict__ tin,
                                                int* __restrict__ pos, int2* __restrict__ edata) {
  int i = blockIdx.x * 256 + threadIdx.x;
  if (i >= ETOT) return;
  int e0, e1, t1, t2f;
  if (i < NEDGE) {
    e0 = el[i]; e1 = el[NEDGE + i]; t1 = et[i]; t2f = 0;
  } else {
    const int* q = tin + (size_t)(i - NEDGE) * 4;
    e0 = q[3]; e1 = q[0]; t1 = q[1]; t2f = q[2] + 1;
  }
  int slot = atomicAdd(&pos[e0], 1);
  edata[slot] = make_int2(e1 | (t1 << 16), t2f);
}

// wave-aggregated list append
__global__ __launch_bounds__(256) void buildLists(const int* __restrict__ offs,
                                                  int* __restrict__ lightL, int* __restrict__ heavyL,
                                                  int* __restrict__ cnts) {
  int i = blockIdx.x * 256 + threadIdx.x;
  int lane = threadIdx.x & 63;
  bool valid = (i < NN);
  int d = valid ? (offs[i + 1] - offs[i]) : 0;
  bool heavy = valid && (d > 64);
  bool light = valid && (d <= 64);
  unsigned long long mh = __ballot(heavy);
  unsigned long long ml = __ballot(light);
  unsigned long long below = (1ULL << lane) - 1ULL;
  int bh = 0, bl = 0;
  if (lane == 0) {
    if (mh) bh = atomicAdd(&cnts[1], __popcll(mh));
    if (ml) bl = atomicAdd(&cnts[0], __popcll(ml));
  }
  bh = __shfl(bh, 0);
  bl = __shfl(bl, 0);
  if (heavy) heavyL[bh + __popcll(mh & below)] = i;
  if (light) lightL[bl + __popcll(ml & below)] = i;
}

// ---------------- merged layer-1 gather (light waves + heavy blocks), bf16 dstp ----------------
__global__ __launch_bounds__(512) void gather1M(const int* __restrict__ lightL, const int* __restrict__ heavyL,
    const int* __restrict__ cnts, const int* __restrict__ offs, const int2* __restrict__ edata,
    const float* __restrict__ srcp, const unsigned short* __restrict__ dstb, const float* __restrict__ relp,
    const float* __restrict__ ssrc, const float* __restrict__ sdst, const float* __restrict__ srel,
    unsigned short* __restrict__ xbf) {
  __shared__ float part[8][208];
  int w = threadIdx.x >> 6, lane = threadIdx.x & 63;
  int c0 = lane, c1 = lane + 64, c2 = lane + 128, c3 = lane + 192;
  if (blockIdx.x < LB1) {
    int widx = blockIdx.x * 8 + w;
    if (widx >= cnts[0]) return;
    int node = lightL[widx];
    int s = offs[node], e = offs[node + 1];
    float s00 = ssrc[node * 2], s01 = ssrc[node * 2 + 1];
    float acc0 = 0.f, acc1 = 0.f, acc2 = 0.f, acc3 = 0.f, rs0 = 0.f, rs1 = 0.f;
    for (int q = s; q < e; ++q) {
      int2 ed = edata[q];
      unsigned w0 = (unsigned)ed.x;
      int e1 = (int)(w0 & 0xFFFFu);
      int t1 = (int)(w0 >> 16);
      int t2f = ed.y;
      float p0 = s00 + sdst[e1 * 2]     + srel[t1 * 2];
      float p1 = s01 + sdst[e1 * 2 + 1] + srel[t1 * 2 + 1];
      const unsigned short* rd = dstb + (size_t)e1 * 200;
      const float* r1 = relp + t1 * 200;
      float m0, m1, m2, m3;
      if (t2f) {
        int t2 = t2f - 1;
        p0 += srel[t2 * 2]; p1 += srel[t2 * 2 + 1];
        const float* r2 = relp + t2 * 200;
        m0 = b2f(rd[c0]) + r1[c0] + r2[c0];
        m1 = b2f(rd[c1]) + r1[c1] + r2[c1];
        m2 = b2f(rd[c2]) + r1[c2] + r2[c2];
        m3 = (c3 < 200) ? b2f(rd[c3]) + r1[c3] + r2[c3] : 0.f;
      } else {
        m0 = b2f(rd[c0]) + r1[c0];
        m1 = b2f(rd[c1]) + r1[c1];
        m2 = b2f(rd[c2]) + r1[c2];
        m3 = (c3 < 200) ? b2f(rd[c3]) + r1[c3] : 0.f;
      }
      p0 = (p0 > 0.f) ? p0 : 0.2f * p0;
      p1 = (p1 > 0.f) ? p1 : 0.2f * p1;
      float ee0 = __expf(-p0), ee1 = __expf(-p1);
      rs0 += ee0; rs1 += ee1;
      acc0 += ee0 * m0;
      acc1 += ((c1 < 100) ? ee0 : ee1) * m1;
      acc2 += ee1 * m2;
      acc3 += ee1 * m3;
    }
    bool has = (e > s);
    float inv0 = has ? 1.f / rs0 : 0.f;
    float inv1 = has ? 1.f / rs1 : 0.f;
    const float* sp = srcp + (size_t)node * 200;
    unsigned short* xo = xbf + (size_t)node * 224;
    float v;
    v = has ? sp[c0] + acc0 * inv0 : 0.f;                       v = (v > 0.f) ? v : expm1f(v); xo[c0] = bf16rne(v);
    v = has ? sp[c1] + acc1 * ((c1 < 100) ? inv0 : inv1) : 0.f; v = (v > 0.f) ? v : expm1f(v); xo[c1] = bf16rne(v);
    v = has ? sp[c2] + acc2 * inv1 : 0.f;                       v = (v > 0.f) ? v : expm1f(v); xo[c2] = bf16rne(v);
    if (c3 < 200) {
      v = has ? sp[c3] + acc3 * inv1 : 0.f;
      v = (v > 0.f) ? v : expm1f(v);
      xo[c3] = bf16rne(v);
    } else if (c3 < 224) {
      xo[c3] = 0;
    }
    return;
  }
  int hidx = blockIdx.x - LB1;
  if (hidx >= cnts[1]) return;
  int node = heavyL[hidx];
  int s = offs[node], e = offs[node + 1];
  float s00 = ssrc[node * 2], s01 = ssrc[node * 2 + 1];
  float acc0 = 0.f, acc1 = 0.f, acc2 = 0.f, acc3 = 0.f, rs0 = 0.f, rs1 = 0.f;
  for (int q = s + w; q < e; q += 8) {
    int2 ed = edata[q];
    unsigned w0 = (unsigned)ed.x;
    int e1 = (int)(w0 & 0xFFFFu);
    int t1 = (int)(w0 >> 16);
    int t2f = ed.y;
    float p0 = s00 + sdst[e1 * 2]     + srel[t1 * 2];
    float p1 = s01 + sdst[e1 * 2 + 1] + srel[t1 * 2 + 1];
    const unsigned short* rd = dstb + (size_t)e1 * 200;
    const float* r1 = relp + t1 * 200;
    float m0, m1, m2, m3;
    if (t2f) {
      int t2 = t2f - 1;
      p0 += srel[t2 * 2]; p1 += srel[t2 * 2 + 1];
      const float* r2 = relp + t2 * 200;
      m0 = b2f(rd[c0]) + r1[c0] + r2[c0];
      m1 = b2f(rd[c1]) + r1[c1] + r2[c1];
      m2 = b2f(rd[c2]) + r1[c2] + r2[c2];
      m3 = (c3 < 200) ? b2f(rd[c3]) + r1[c3] + r2[c3] : 0.f;
    } else {
      m0 = b2f(rd[c0]) + r1[c0];
      m1 = b2f(rd[c1]) + r1[c1];
      m2 = b2f(rd[c2]) + r1[c2];
      m3 = (c3 < 200) ? b2f(rd[c3]) + r1[c3] : 0.f;
    }
    p0 = (p0 > 0.f) ? p0 : 0.2f * p0;
    p1 = (p1 > 0.f) ? p1 : 0.2f * p1;
    float ee0 = __expf(-p0), ee1 = __expf(-p1);
    rs0 += ee0; rs1 += ee1;
    acc0 += ee0 * m0;
    acc1 += ((c1 < 100) ? ee0 : ee1) * m1;
    acc2 += ee1 * m2;
    acc3 += ee1 * m3;
  }
  part[w][c0] = acc0; part[w][c1] = acc1; part[w][c2] = acc2;
  if (c3 < 200) part[w][c3] = acc3;
  if (lane == 0) { part[w][200] = rs0; part[w][201] = rs1; }
  __syncthreads();
  int t = threadIdx.x;
  if (t < 224) {
    unsigned short outv = 0;
    if (t < 200) {
      float a = 0.f, r0 = 0.f, r1 = 0.f;
      #pragma unroll
      for (int wv = 0; wv < 8; ++wv) { a += part[wv][t]; r0 += part[wv][200]; r1 += part[wv][201]; }
      float inv = (t < 100) ? 1.f / r0 : 1.f / r1;
      float v = srcp[(size_t)node * 200 + t] + a * inv;
      v = (v > 0.f) ? v : expm1f(v);
      outv = bf16rne(v);
    }
    xbf[(size_t)node * 224 + t] = outv;
  }
}

// ---------------- merged layer-2 gather, bf16 dstp ----------------
__global__ __launch_bounds__(512) void gather2M(const int* __restrict__ lightL, const int* __restrict__ heavyL,
    const int* __restrict__ cnts, const int* __restrict__ offs, const int2* __restrict__ edata,
    const float* __restrict__ srcp, const unsigned short* __restrict__ dstb, const float* __restrict__ relp,
    const float* __restrict__ ssrc, const float* __restrict__ sdst, const float* __restrict__ srel,
    float* __restrict__ hout) {
  __shared__ float part[8][208];
  int w = threadIdx.x >> 6, lane = threadIdx.x & 63;
  int c0 = lane, c1 = lane + 64, c2 = lane + 128, c3 = lane + 192;
  if (blockIdx.x < LB1) {
    int widx = blockIdx.x * 8 + w;
    if (widx >= cnts[0]) return;
    int node = lightL[widx];
    int s = offs[node], e = offs[node + 1];
    float s0 = ssrc[node];
    float acc0 = 0.f, acc1 = 0.f, acc2 = 0.f, acc3 = 0.f, rs = 0.f;
    for (int q = s; q < e; ++q) {
      int2 ed = edata[q];
      unsigned w0 = (unsigned)ed.x;
      int e1 = (int)(w0 & 0xFFFFu);
      int t1 = (int)(w0 >> 16);
      int t2f = ed.y;
      float p = s0 + sdst[e1] + srel[t1];
      const unsigned short* rd = dstb + (size_t)e1 * 200;
      const float* r1 = relp + t1 * 200;
      float m0, m1, m2, m3;
      if (t2f) {
        int t2 = t2f - 1;
        p += srel[t2];
        const float* r2 = relp + t2 * 200;
        m0 = b2f(rd[c0]) + r1[c0] + r2[c0];
        m1 = b2f(rd[c1]) + r1[c1] + r2[c1];
        m2 = b2f(rd[c2]) + r1[c2] + r2[c2];
        m3 = (c3 < 200) ? b2f(rd[c3]) + r1[c3] + r2[c3] : 0.f;
      } else {
        m0 = b2f(rd[c0]) + r1[c0];
        m1 = b2f(rd[c1]) + r1[c1];
        m2 = b2f(rd[c2]) + r1[c2];
        m3 = (c3 < 200) ? b2f(rd[c3]) + r1[c3] : 0.f;
      }
      p = (p > 0.f) ? p : 0.2f * p;
      float ee = __expf(-p);
      rs += ee;
      acc0 += ee * m0; acc1 += ee * m1; acc2 += ee * m2; acc3 += ee * m3;
    }
    bool has = (e > s);
    float inv = has ? 1.f / rs : 0.f;
    const float* sp = srcp + (size_t)node * 200;
    float* ho = hout + (size_t)node * 200;
    float v;
    v = has ? sp[c0] + acc0 * inv : 0.f; ho[c0] = (v > 0.f) ? v : expm1f(v);
    v = has ? sp[c1] + acc1 * inv : 0.f; ho[c1] = (v > 0.f) ? v : expm1f(v);
    v = has ? sp[c2] + acc2 * inv : 0.f; ho[c2] = (v > 0.f) ? v : expm1f(v);
    if (c3 < 200) {
      v = has ? sp[c3] + acc3 * inv : 0.f;
      ho[c3] = (v > 0.f) ? v : expm1f(v);
    }
    return;
  }
  int hidx = blockIdx.x - LB1;
  if (hidx >= cnts[1]) return;
  int node = heavyL[hidx];
  int s = offs[node], e = offs[node + 1];
  float s0 = ssrc[node];
  float acc0 = 0.f, acc1 = 0.f, acc2 = 0.f, acc3 = 0.f, rs = 0.f;
  for (int q = s + w; q < e; q += 8) {
    int2 ed = edata[q];
    unsigned w0 = (unsigned)ed.x;
    int e1 = (int)(w0 & 0xFFFFu);
    int t1 = (int)(w0 >> 16);
    int t2f = ed.y;
    float p = s0 + sdst[e1] + srel[t1];
    const unsigned short* rd = dstb + (size_t)e1 * 200;
    const float* r1 = relp + t1 * 200;
    float m0, m1, m2, m3;
    if (t2f) {
      int t2 = t2f - 1;
      p += srel[t2];
      const float* r2 = relp + t2 * 200;
      m0 = b2f(rd[c0]) + r1[c0] + r2[c0];
      m1 = b2f(rd[c1]) + r1[c1] + r2[c1];
      m2 = b2f(rd[c2]) + r1[c2] + r2[c2];
      m3 = (c3 < 200) ? b2f(rd[c3]) + r1[c3] + r2[c3] : 0.f;
    } else {
      m0 = b2f(rd[c0]) + r1[c0];
      m1 = b2f(rd[c1]) + r1[c1];
      m2 = b2f(rd[c2]) + r1[c2];
      m3 = (c3 < 200) ? b2f(rd[c3]) + r1[c3] : 0.f;
    }
    p = (p > 0.f) ? p : 0.2f * p;
    float ee = __expf(-p);
    rs += ee;
    acc0 += ee * m0; acc1 += ee * m1; acc2 += ee * m2; acc3 += ee * m3;
  }
  part[w][c0] = acc0; part[w][c1] = acc1; part[w][c2] = acc2;
  if (c3 < 200) part[w][c3] = acc3;
  if (lane == 0) part[w][200] = rs;
  __syncthreads();
  int t = threadIdx.x;
  if (t < 200) {
    float a = 0.f, r = 0.f;
    #pragma unroll
    for (int wv = 0; wv < 8; ++wv) { a += part[wv][t]; r += part[wv][200]; }
    float v = srcp[(size_t)node * 200 + t] + a / r;
    hout[(size_t)node * 200 + t] = (v > 0.f) ? v : expm1f(v);
  }
}

// ---------------- pad xbf rows [NN, MP) ----------------
__global__ __launch_bounds__(256) void padx(unsigned short* __restrict__ xbf) {
  int i = blockIdx.x * 256 + threadIdx.x;
  if (i < (MP - NN) * 224) xbf[(size_t)NN * 224 + i] = 0;
}

// ---------------- mask scatter ----------------
__global__ __launch_bounds__(256) void maskset(const int* __restrict__ bi, float* __restrict__ maskA) {
  int t = blockIdx.x * 256 + threadIdx.x;
  if (t < BATCH) maskA[bi[t * 3 + 2]] = 1.0f;
}

// ---------------- final: out = l2norm(xw + mask*h2), in place ----------------
__global__ __launch_bounds__(256) void finalk2(const float* __restrict__ xw, const float* __restrict__ h2,
                                               const float* __restrict__ maskA, float* __restrict__ out) {
  int row  = blockIdx.x * 4 + (threadIdx.x >> 6);
  int lane = threadIdx.x & 63;
  if (row >= NN) return;
  float m = maskA[row];
  const float* xr = xw + (size_t)row * 200;
  const float* hr = h2 + (size_t)row * 200;
  int c0 = lane, c1 = lane + 64, c2 = lane + 128, c3 = lane + 192;
  float v0 = xr[c0] + m * hr[c0];
  float v1 = xr[c1] + m * hr[c1];
  float v2 = xr[c2] + m * hr[c2];
  float v3 = (c3 < 200) ? xr[c3] + m * hr[c3] : 0.f;
  float ss = v0 * v0 + v1 * v1 + v2 * v2 + v3 * v3;
  #pragma unroll
  for (int off = 1; off < 64; off <<= 1) ss += __shfl_xor(ss, off);
  float inv = 1.f / fmaxf(sqrtf(ss), 1e-12f);
  float* o = out + (size_t)row * 200;
  o[c0] = v0 * inv; o[c1] = v1 * inv; o[c2] = v2 * inv;
  if (c3 < 200) o[c3] = v3 * inv;
}

extern "C" void kernel_launch(void* const* d_in, const int* in_sizes, int n_in,
                              void* d_out, int out_size, void* d_ws, size_t ws_size,
                              hipStream_t stream) {
  (void)in_sizes; (void)n_in; (void)out_size; (void)ws_size;
  const float* ent      = (const float*)d_in[0];
  const float* rel      = (const float*)d_in[1];
  const float* a_heads  = (const float*)d_in[3];
  const float* a2_heads = (const float*)d_in[4];
  const float* W_gat    = (const float*)d_in[5];
  const float* a_out    = (const float*)d_in[6];
  const float* a2_out   = (const float*)d_in[7];
  const float* W_ent    = (const float*)d_in[8];
  const int* edge_list  = (const int*)d_in[9];
  const int* edge_type  = (const int*)d_in[10];
  const int* tin        = (const int*)d_in[11];
  const int* binp       = (const int*)d_in[12];

  float* out    = (float*)d_out;
  float* outrel = out + 10000000;     // (500,200)

  float* ws    = (float*)d_ws;
  float* bufS  = ws;                               // 10M f32: srcp1 -> srcp2 -> h2
  unsigned short* dstD = (unsigned short*)(ws + 10000000); // NN*200 bf16 (dstp1 then dstp2)
  float* relp1 = ws + 15000000;       // 100k
  float* relp2 = ws + 15100000;       // 100k
  float* ssrc1 = ws + 15200000;       // N*2
  float* sdst1 = ws + 15300000;       // N*2
  float* s2src = ws + 15400000;       // N
  float* s2dst = ws + 15450000;       // N
  float* srel1 = ws + 15500000;       // 1000
  float* s2rel = ws + 15501000;       // 500
  float* maskA = ws + 15502000;       // N
  unsigned short* x0nbf = (unsigned short*)(ws + 15560000); // MP*128 bf16
  unsigned short* xbf   = (unsigned short*)(ws + 18800000); // MP*224 bf16
  unsigned short* B1s   = (unsigned short*)(ws + 24450000); // 208*128
  unsigned short* B1d   = (unsigned short*)(ws + 24470000);
  unsigned short* Bxw   = (unsigned short*)(ws + 24490000);
  unsigned short* B2s   = (unsigned short*)(ws + 24510000); // 208*224
  unsigned short* B2d   = (unsigned short*)(ws + 24540000);
  int* ibase  = (int*)(ws + 24600000);
  int* deg    = ibase;                // 50k
  int* offs   = ibase + 50000;        // 50k+1
  int* pos    = ibase + 100016;       // 50k
  int* bsum   = ibase + 150016;       // 256
  int* cnts   = ibase + 150272;       // 2 (+pad)
  int* lightL = ibase + 150280;       // 50k
  int* heavyL = ibase + 200280;       // 50k (+pad)
  int2* edata = (int2*)(ibase + 250288); // 375k int2

  hipMemsetAsync(deg,   0, (size_t)NN * 4, stream);
  hipMemsetAsync(maskA, 0, (size_t)NN * 4, stream);
  hipMemsetAsync(cnts,  0, 8, stream);

  l2norm_bf16<<<12512, 256, 0, stream>>>(ent, x0nbf);

  // CSR + lists
  histk<<<(ETOT + 255) / 256, 256, 0, stream>>>(edge_list, tin, deg);
  scanA<<<196, 256, 0, stream>>>(deg, bsum, NN);
  scanB<<<1, 256, 0, stream>>>(bsum, 196);
  scanC<<<196, 256, 0, stream>>>(deg, bsum, offs, pos, NN, ETOT);
  scatterk<<<(ETOT + 255) / 256, 256, 0, stream>>>(edge_list, edge_type, tin, pos, edata);
  buildLists<<<196, 256, 0, stream>>>(offs, lightL, heavyL, cnts);

  // weight conversion
  convB1<<<104, 256, 0, stream>>>(a_heads, 0,   B1s);
  convB1<<<104, 256, 0, stream>>>(a_heads, 100, B1d);
  convBg<<<104, 256, 0, stream>>>(W_ent, 1, 200, 200, 100, 128, Bxw);
  convBg<<<182, 256, 0, stream>>>(a_out,       600, 1, 200, 200, 224, B2s);
  convBg<<<182, 256, 0, stream>>>(a_out + 200, 600, 1, 200, 200, 224, B2d);

  // layer-1 projections + xw, one 3-job launch
  {
    GJob js = {B1s, bufS, nullptr, a2_heads, ssrc1, 1};
    GJob jd = {B1d, nullptr, dstD, a2_heads, sdst1, 1};
    GJob jx = {Bxw, out, nullptr, nullptr, nullptr, 0};
    dim3 g(391, 3);
    gemm_multi<128><<<g, 256, 0, stream>>>(x0nbf, js, jd, jx, NN);
  }

  // rel projections (f32, small) + rel dots
  dim3 g2(2, 4);
  gemm2_f32<<<g2, 256, 0, stream>>>(rel, NRELS, 100, 100, a_heads + 200,         300, 1, relp1, 200, 100, 0);
  gemm2_f32<<<g2, 256, 0, stream>>>(rel, NRELS, 100, 100, a_heads + 30000 + 200, 300, 1, relp1, 200, 100, 100);
  dot2h<<<125, 256, 0, stream>>>(relp1, a2_heads, srel1, NRELS);

  gather1M<<<LB1 + HBMAX, 512, 0, stream>>>(lightL, heavyL, cnts, offs, edata,
                                            bufS, dstD, relp1, ssrc1, sdst1, srel1, xbf);
  padx<<<42, 256, 0, stream>>>(xbf);

  // layer-2 projections, one 2-job launch (overwrites bufS/dstD)
  {
    GJob js = {B2s, bufS, nullptr, a2_out, s2src, 2};
    GJob jd = {B2d, nullptr, dstD, a2_out, s2dst, 2};
    GJob jz = {B2s, nullptr, nullptr, nullptr, nullptr, 0};
    dim3 g(391, 2);
    gemm_multi<224><<<g, 256, 0, stream>>>(xbf, js, jd, jz, NN);
  }

  // out_relation_1, relp2, rel dot
  dim3 g3(4, 4);
  gemm2_f32<<<g3, 256, 0, stream>>>(rel, NRELS, 100, 100, W_gat, 1, 200, outrel, 200, 200, 0);
  gemm2_f32<<<g3, 256, 0, stream>>>(outrel, NRELS, 200, 200, a_out + 400, 600, 1, relp2, 200, 200, 0);
  dot1<<<125, 256, 0, stream>>>(relp2, a2_out, s2rel, NRELS);

  maskset<<<256, 256, 0, stream>>>(binp, maskA);

  gather2M<<<LB1 + HBMAX, 512, 0, stream>>>(lightL, heavyL, cnts, offs, edata,
                                            bufS, dstD, relp2, s2src, s2dst, s2rel, bufS);

  finalk2<<<12500, 256, 0, stream>>>(out, bufS, maskA, out);
}

// Round 7
// 640.609 us; speedup vs baseline: 1.9812x; 1.0186x over previous
//
#include <hip/hip_runtime.h>
#include <math.h>

#define NN    50000
#define MP    50048    // padded rows (391*128)
#define NEDGE 250000
#define NHOPE 125000
#define ETOT  375000
#define NRELS 500
#define BATCH 65536
#define LB1   6250     // light blocks (8 waves each -> 50000 waves)
#define HBMAX 5769     // max heavy nodes (deg>64): 375000/65

typedef __attribute__((ext_vector_type(8))) short bf16x8;
typedef __attribute__((ext_vector_type(4))) float f32x4;

__device__ __forceinline__ unsigned short bf16rne(float f) {
  unsigned u = __float_as_uint(f);
  unsigned r = (u + 0x7FFFu + ((u >> 16) & 1u)) >> 16;
  return (unsigned short)r;
}
__device__ __forceinline__ float b2f(unsigned short u) {
  return __uint_as_float(((unsigned)u) << 16);
}

struct GJob {
  const unsigned short* B;   // 208 x KP bf16
  float* Cf;                 // f32 out (ld 200) or null
  unsigned short* Cbf;       // bf16 out (ld 200) or null
  const float* a2;           // 200 floats or null
  float* dot;                // per-row scalar(s) or null
  int dotmode;               // 1 = split at 100 (two heads), 2 = single sum
};

// ---------------- l2norm -> bf16 padded (MP x 128) ----------------
__global__ __launch_bounds__(256) void l2norm_bf16(const float* __restrict__ in,
                                                   unsigned short* __restrict__ out) {
  int row  = blockIdx.x * 4 + (threadIdx.x >> 6);
  int lane = threadIdx.x & 63;
  if (row >= MP) return;
  unsigned short* o = out + (size_t)row * 128;
  if (row >= NN) { o[lane] = 0; o[lane + 64] = 0; return; }
  const float* r = in + (size_t)row * 100;
  float v0 = r[lane];
  float v1 = (lane + 64 < 100) ? r[lane + 64] : 0.f;
  float ss = v0 * v0 + v1 * v1;
  #pragma unroll
  for (int off = 1; off < 64; off <<= 1) ss += __shfl_xor(ss, off);
  float inv = 1.f / fmaxf(sqrtf(ss), 1e-12f);
  o[lane] = bf16rne(v0 * inv);
  o[lane + 64] = (lane + 64 < 100) ? bf16rne(v1 * inv) : (unsigned short)0;
}

// ---------------- multi-job bf16 MFMA GEMM with fused epilogue ----------------
template<int KP>
__global__ __launch_bounds__(256) void gemm_multi(const unsigned short* __restrict__ A,
                                                  GJob j0, GJob j1, GJob j2, int M) {
  GJob jb = (blockIdx.y == 0) ? j0 : ((blockIdx.y == 1) ? j1 : j2);
  int wave = threadIdx.x >> 6, lane = threadIdx.x & 63;
  int rb = blockIdx.x * 128 + wave * 32;
  int rl = lane & 15;
  int kq = (lane >> 4) * 8;
  const unsigned short* a0p = A + (size_t)(rb + rl) * KP + kq;
  const unsigned short* a1p = a0p + (size_t)16 * KP;
  const unsigned short* bp  = jb.B + (size_t)rl * KP + kq;
  f32x4 acc[2][13];
  #pragma unroll
  for (int i = 0; i < 2; ++i)
    #pragma unroll
    for (int t = 0; t < 13; ++t) acc[i][t] = (f32x4){0.f, 0.f, 0.f, 0.f};
  #pragma unroll 2
  for (int ks = 0; ks < KP; ks += 32) {
    bf16x8 a0 = *(const bf16x8*)(a0p + ks);
    bf16x8 a1 = *(const bf16x8*)(a1p + ks);
    #pragma unroll
    for (int t = 0; t < 13; ++t) {
      bf16x8 b = *(const bf16x8*)(bp + (size_t)t * 16 * KP + ks);
      acc[0][t] = __builtin_amdgcn_mfma_f32_16x16x32_bf16(a0, b, acc[0][t], 0, 0, 0);
      acc[1][t] = __builtin_amdgcn_mfma_f32_16x16x32_bf16(a1, b, acc[1][t], 0, 0, 0);
    }
  }
  int rg = (lane >> 4) * 4;
  if (jb.Cf) {
    #pragma unroll
    for (int rt = 0; rt < 2; ++rt) {
      int row0 = rb + rt * 16 + rg;
      #pragma unroll
      for (int t = 0; t < 13; ++t) {
        int col = t * 16 + rl;
        if (col < 200) {
          #pragma unroll
          for (int g = 0; g < 4; ++g) {
            int row = row0 + g;
            if (row < M) jb.Cf[(size_t)row * 200 + col] = acc[rt][t][g];
          }
        }
      }
    }
  }
  if (jb.Cbf) {
    #pragma unroll
    for (int rt = 0; rt < 2; ++rt) {
      int row0 = rb + rt * 16 + rg;
      #pragma unroll
      for (int t = 0; t < 13; ++t) {
        int col = t * 16 + rl;
        if (col < 200) {
          #pragma unroll
          for (int g = 0; g < 4; ++g) {
            int row = row0 + g;
            if (row < M) jb.Cbf[(size_t)row * 200 + col] = bf16rne(acc[rt][t][g]);
          }
        }
      }
    }
  }
  if (jb.dot) {
    #pragma unroll
    for (int rt = 0; rt < 2; ++rt) {
      float p0[4] = {0.f, 0.f, 0.f, 0.f}, p1[4] = {0.f, 0.f, 0.f, 0.f};
      #pragma unroll
      for (int t = 0; t < 13; ++t) {
        int col = t * 16 + rl;
        float av = (col < 200) ? jb.a2[col] : 0.f;
        bool lo = (col < 100);
        #pragma unroll
        for (int g = 0; g < 4; ++g) {
          float v = acc[rt][t][g] * av;
          if (lo) p0[g] += v; else p1[g] += v;
        }
      }
      #pragma unroll
      for (int off = 1; off < 16; off <<= 1) {
        #pragma unroll
        for (int g = 0; g < 4; ++g) {
          p0[g] += __shfl_xor(p0[g], off);
          p1[g] += __shfl_xor(p1[g], off);
        }
      }
      if (rl == 0) {
        int row0 = rb + rt * 16 + rg;
        #pragma unroll
        for (int g = 0; g < 4; ++g) {
          int row = row0 + g;
          if (row < M) {
            if (jb.dotmode == 1) { jb.dot[row * 2] = p0[g]; jb.dot[row * 2 + 1] = p1[g]; }
            else                 { jb.dot[row] = p0[g] + p1[g]; }
          }
        }
      }
    }
  }
}

// ---------------- weight conversion to bf16 k-major padded ----------------
__global__ __launch_bounds__(256) void convB1(const float* __restrict__ ah, int koff,
                                              unsigned short* __restrict__ dst) {
  int idx = blockIdx.x * 256 + threadIdx.x;
  if (idx >= 208 * 128) return;
  int j = idx >> 7, k = idx & 127;
  float v = 0.f;
  if (j < 200 && k < 100) {
    const float* s = ah + ((j < 100) ? 0 : 30000) + (j % 100) * 300 + koff;
    v = s[k];
  }
  dst[idx] = bf16rne(v);
}

__global__ __launch_bounds__(256) void convBg(const float* __restrict__ src, int wsj, int wsk,
                                              int rows, int K, int Kp,
                                              unsigned short* __restrict__ dst) {
  int idx = blockIdx.x * 256 + threadIdx.x;
  if (idx >= 208 * Kp) return;
  int j = idx / Kp, k = idx - j * Kp;
  float v = (j < rows && k < K) ? src[(size_t)j * wsj + (size_t)k * wsk] : 0.f;
  dst[idx] = bf16rne(v);
}

// ---------------- f32 GEMM (small, rel matrices) ----------------
__global__ __launch_bounds__(256) void gemm2_f32(const float* __restrict__ A, int M, int Kd, int lda,
                                                 const float* __restrict__ W, int wsj, int wsk,
                                                 float* __restrict__ C, int ldc, int Ncols, int col0) {
  __shared__ float As[16][132];
  __shared__ float Bs[16][68];
  int tid = threadIdx.x;
  int tx = tid & 15, ty = tid >> 4;
  int row0 = blockIdx.y * 128;
  int colb = blockIdx.x * 64;
  float acc[8][4];
  #pragma unroll
  for (int i = 0; i < 8; ++i)
    #pragma unroll
    for (int j = 0; j < 4; ++j) acc[i][j] = 0.f;
  for (int kt = 0; kt < Kd; kt += 16) {
    #pragma unroll
    for (int l = 0; l < 8; ++l) {
      int idx = tid + l * 256;
      int m = idx >> 4, k = idx & 15;
      int gm = row0 + m, gk = kt + k;
      As[k][m] = (gm < M && gk < Kd) ? A[(size_t)gm * lda + gk] : 0.f;
    }
    #pragma unroll
    for (int l = 0; l < 4; ++l) {
      int idx = tid + l * 256;
      int j = idx >> 4, k = idx & 15;
      int gj = colb + j, gk = kt + k;
      Bs[k][j] = (gj < Ncols && gk < Kd) ? W[(size_t)gj * wsj + (size_t)gk * wsk] : 0.f;
    }
    __syncthreads();
    #pragma unroll
    for (int k = 0; k < 16; ++k) {
      float4 bv = *(const float4*)&Bs[k][tx * 4];
      float4 a0 = *(const float4*)&As[k][ty * 8];
      float4 a1 = *(const float4*)&As[k][ty * 8 + 4];
      float av[8] = {a0.x, a0.y, a0.z, a0.w, a1.x, a1.y, a1.z, a1.w};
      float bb[4] = {bv.x, bv.y, bv.z, bv.w};
      #pragma unroll
      for (int i = 0; i < 8; ++i)
        #pragma unroll
        for (int j = 0; j < 4; ++j)
          acc[i][j] += av[i] * bb[j];
    }
    __syncthreads();
  }
  int gj0 = colb + tx * 4;
  #pragma unroll
  for (int i = 0; i < 8; ++i) {
    int gm = row0 + ty * 8 + i;
    if (gm >= M) continue;
    float* cp = C + (size_t)gm * ldc + col0;
    #pragma unroll
    for (int j = 0; j < 4; ++j) if (gj0 + j < Ncols) cp[gj0 + j] = acc[i][j];
  }
}

// ---------------- per-row dots (rel rows only) ----------------
__global__ __launch_bounds__(256) void dot2h(const float* __restrict__ P, const float* __restrict__ a2,
                                             float* __restrict__ outp, int M) {
  int row  = blockIdx.x * 4 + (threadIdx.x >> 6);
  int lane = threadIdx.x & 63;
  if (row >= M) return;
  const float* pr = P + (size_t)row * 200;
  float s0 = 0.f, s1 = 0.f;
  for (int k = lane; k < 100; k += 64) {
    s0 += pr[k] * a2[k];
    s1 += pr[100 + k] * a2[100 + k];
  }
  #pragma unroll
  for (int off = 1; off < 64; off <<= 1) { s0 += __shfl_xor(s0, off); s1 += __shfl_xor(s1, off); }
  if (lane == 0) { outp[row * 2] = s0; outp[row * 2 + 1] = s1; }
}

__global__ __launch_bounds__(256) void dot1(const float* __restrict__ P, const float* __restrict__ a2,
                                            float* __restrict__ outp, int M) {
  int row  = blockIdx.x * 4 + (threadIdx.x >> 6);
  int lane = threadIdx.x & 63;
  if (row >= M) return;
  const float* pr = P + (size_t)row * 200;
  float s = 0.f;
  for (int k = lane; k < 200; k += 64) s += pr[k] * a2[k];
  #pragma unroll
  for (int off = 1; off < 64; off <<= 1) s += __shfl_xor(s, off);
  if (lane == 0) outp[row] = s;
}

// ---------------- CSR build ----------------
__global__ __launch_bounds__(256) void histk(const int* __restrict__ el, const int* __restrict__ tin,
                                             int* __restrict__ deg) {
  int i = blockIdx.x * 256 + threadIdx.x;
  if (i >= ETOT) return;
  int e0 = (i < NEDGE) ? el[i] : tin[(size_t)(i - NEDGE) * 4 + 3];
  atomicAdd(&deg[e0], 1);
}

__global__ __launch_bounds__(256) void scanA(const int* __restrict__ deg, int* __restrict__ bsum, int n) {
  __shared__ int s[256];
  int t = threadIdx.x;
  int i = blockIdx.x * 256 + t;
  s[t] = (i < n) ? deg[i] : 0;
  __syncthreads();
  for (int off = 128; off > 0; off >>= 1) {
    if (t < off) s[t] += s[t + off];
    __syncthreads();
  }
  if (t == 0) bsum[blockIdx.x] = s[0];
}

__global__ __launch_bounds__(256) void scanB(int* __restrict__ bsum, int nb) {
  __shared__ int s[256];
  int t = threadIdx.x;
  int v = (t < nb) ? bsum[t] : 0;
  s[t] = v;
  __syncthreads();
  for (int off = 1; off < 256; off <<= 1) {
    int add = (t >= off) ? s[t - off] : 0;
    __syncthreads();
    s[t] += add;
    __syncthreads();
  }
  if (t < nb) bsum[t] = s[t] - v;  // exclusive
}

__global__ __launch_bounds__(256) void scanC(const int* __restrict__ deg, const int* __restrict__ bsum,
                                             int* __restrict__ offs, int* __restrict__ pos, int n, int total) {
  __shared__ int s[256];
  int t = threadIdx.x;
  int i = blockIdx.x * 256 + t;
  int v = (i < n) ? deg[i] : 0;
  s[t] = v;
  __syncthreads();
  for (int off = 1; off < 256; off <<= 1) {
    int add = (t >= off) ? s[t - off] : 0;
    __syncthreads();
    s[t] += add;
    __syncthreads();
  }
  if (i < n) {
    int e = bsum[blockIdx.x] + s[t] - v;
    offs[i] = e;
    pos[i]  = e;
  }
  if (i == 0) offs[n] = total;
}

__global__ __launch_bounds__(256) void scatterk(const int* __restrict__ el, const int* __restrict__ et,
                                                const int* __restrict__ tin,
                                                int* __restrict__ pos, int2* __restrict__ edata) {
  int i = blockIdx.x * 256 + threadIdx.x;
  if (i >= ETOT) return;
  int e0, e1, t1, t2f;
  if (i < NEDGE) {
    e0 = el[i]; e1 = el[NEDGE + i]; t1 = et[i]; t2f = 0;
  } else {
    const int* q = tin + (size_t)(i - NEDGE) * 4;
    e0 = q[3]; e1 = q[0]; t1 = q[1]; t2f = q[2] + 1;
  }
  int slot = atomicAdd(&pos[e0], 1);
  edata[slot] = make_int2(e1 | (t1 << 16), t2f);
}

// wave-aggregated list append
__global__ __launch_bounds__(256) void buildLists(const int* __restrict__ offs,
                                                  int* __restrict__ lightL, int* __restrict__ heavyL,
                                                  int* __restrict__ cnts) {
  int i = blockIdx.x * 256 + threadIdx.x;
  int lane = threadIdx.x & 63;
  bool valid = (i < NN);
  int d = valid ? (offs[i + 1] - offs[i]) : 0;
  bool heavy = valid && (d > 64);
  bool light = valid && (d <= 64);
  unsigned long long mh = __ballot(heavy);
  unsigned long long ml = __ballot(light);
  unsigned long long below = (1ULL << lane) - 1ULL;
  int bh = 0, bl = 0;
  if (lane == 0) {
    if (mh) bh = atomicAdd(&cnts[1], __popcll(mh));
    if (ml) bl = atomicAdd(&cnts[0], __popcll(ml));
  }
  bh = __shfl(bh, 0);
  bl = __shfl(bl, 0);
  if (heavy) heavyL[bh + __popcll(mh & below)] = i;
  if (light) lightL[bl + __popcll(ml & below)] = i;
}

// ---------------- merged layer-1 gather (heavy-first), bf16 dstp, unroll-2 ----------------
__global__ __launch_bounds__(512) void gather1M(const int* __restrict__ lightL, const int* __restrict__ heavyL,
    const int* __restrict__ cnts, const int* __restrict__ offs, const int2* __restrict__ edata,
    const float* __restrict__ srcp, const unsigned short* __restrict__ dstb, const float* __restrict__ relp,
    const float* __restrict__ ssrc, const float* __restrict__ sdst, const float* __restrict__ srel,
    unsigned short* __restrict__ xbf) {
  __shared__ float part[8][208];
  int w = threadIdx.x >> 6, lane = threadIdx.x & 63;
  int c0 = lane, c1 = lane + 64, c2 = lane + 128, c3 = lane + 192;
  float acc0 = 0.f, acc1 = 0.f, acc2 = 0.f, acc3 = 0.f, rs0 = 0.f, rs1 = 0.f;
  float s00, s01;
  auto edgeop = [&](int2 ed) {
    unsigned w0 = (unsigned)ed.x;
    int e1 = (int)(w0 & 0xFFFFu);
    int t1 = (int)(w0 >> 16);
    int t2f = ed.y;
    float p0 = s00 + sdst[e1 * 2]     + srel[t1 * 2];
    float p1 = s01 + sdst[e1 * 2 + 1] + srel[t1 * 2 + 1];
    const unsigned short* rd = dstb + (size_t)e1 * 200;
    const float* r1 = relp + t1 * 200;
    float m0, m1, m2, m3;
    if (t2f) {
      int t2 = t2f - 1;
      p0 += srel[t2 * 2]; p1 += srel[t2 * 2 + 1];
      const float* r2 = relp + t2 * 200;
      m0 = b2f(rd[c0]) + r1[c0] + r2[c0];
      m1 = b2f(rd[c1]) + r1[c1] + r2[c1];
      m2 = b2f(rd[c2]) + r1[c2] + r2[c2];
      m3 = (c3 < 200) ? b2f(rd[c3]) + r1[c3] + r2[c3] : 0.f;
    } else {
      m0 = b2f(rd[c0]) + r1[c0];
      m1 = b2f(rd[c1]) + r1[c1];
      m2 = b2f(rd[c2]) + r1[c2];
      m3 = (c3 < 200) ? b2f(rd[c3]) + r1[c3] : 0.f;
    }
    p0 = (p0 > 0.f) ? p0 : 0.2f * p0;
    p1 = (p1 > 0.f) ? p1 : 0.2f * p1;
    float ee0 = __expf(-p0), ee1 = __expf(-p1);
    rs0 += ee0; rs1 += ee1;
    acc0 += ee0 * m0;
    acc1 += ((c1 < 100) ? ee0 : ee1) * m1;
    acc2 += ee1 * m2;
    acc3 += ee1 * m3;
  };
  if (blockIdx.x < HBMAX) {
    int hidx = blockIdx.x;
    if (hidx >= cnts[1]) return;
    int node = heavyL[hidx];
    int s = offs[node], e = offs[node + 1];
    s00 = ssrc[node * 2]; s01 = ssrc[node * 2 + 1];
    int q = s + w;
    for (; q + 8 < e; q += 16) { edgeop(edata[q]); edgeop(edata[q + 8]); }
    if (q < e) edgeop(edata[q]);
    part[w][c0] = acc0; part[w][c1] = acc1; part[w][c2] = acc2;
    if (c3 < 200) part[w][c3] = acc3;
    if (lane == 0) { part[w][200] = rs0; part[w][201] = rs1; }
    __syncthreads();
    int t = threadIdx.x;
    if (t < 224) {
      unsigned short outv = 0;
      if (t < 200) {
        float a = 0.f, r0 = 0.f, r1 = 0.f;
        #pragma unroll
        for (int wv = 0; wv < 8; ++wv) { a += part[wv][t]; r0 += part[wv][200]; r1 += part[wv][201]; }
        float inv = (t < 100) ? 1.f / r0 : 1.f / r1;
        float v = srcp[(size_t)node * 200 + t] + a * inv;
        v = (v > 0.f) ? v : expm1f(v);
        outv = bf16rne(v);
      }
      xbf[(size_t)node * 224 + t] = outv;
    }
    return;
  }
  int widx = (blockIdx.x - HBMAX) * 8 + w;
  if (widx >= cnts[0]) return;
  int node = lightL[widx];
  int s = offs[node], e = offs[node + 1];
  s00 = ssrc[node * 2]; s01 = ssrc[node * 2 + 1];
  int q = s;
  for (; q + 1 < e; q += 2) { edgeop(edata[q]); edgeop(edata[q + 1]); }
  if (q < e) edgeop(edata[q]);
  bool has = (e > s);
  float inv0 = has ? 1.f / rs0 : 0.f;
  float inv1 = has ? 1.f / rs1 : 0.f;
  const float* sp = srcp + (size_t)node * 200;
  unsigned short* xo = xbf + (size_t)node * 224;
  float v;
  v = has ? sp[c0] + acc0 * inv0 : 0.f;                       v = (v > 0.f) ? v : expm1f(v); xo[c0] = bf16rne(v);
  v = has ? sp[c1] + acc1 * ((c1 < 100) ? inv0 : inv1) : 0.f; v = (v > 0.f) ? v : expm1f(v); xo[c1] = bf16rne(v);
  v = has ? sp[c2] + acc2 * inv1 : 0.f;                       v = (v > 0.f) ? v : expm1f(v); xo[c2] = bf16rne(v);
  if (c3 < 200) {
    v = has ? sp[c3] + acc3 * inv1 : 0.f;
    v = (v > 0.f) ? v : expm1f(v);
    xo[c3] = bf16rne(v);
  } else if (c3 < 224) {
    xo[c3] = 0;
  }
}

// ---------------- merged layer-2 gather (heavy-first), bf16 dstp, unroll-2 ----------------
__global__ __launch_bounds__(512) void gather2M(const int* __restrict__ lightL, const int* __restrict__ heavyL,
    const int* __restrict__ cnts, const int* __restrict__ offs, const int2* __restrict__ edata,
    const float* __restrict__ srcp, const unsigned short* __restrict__ dstb, const float* __restrict__ relp,
    const float* __restrict__ ssrc, const float* __restrict__ sdst, const float* __restrict__ srel,
    float* __restrict__ hout) {
  __shared__ float part[8][208];
  int w = threadIdx.x >> 6, lane = threadIdx.x & 63;
  int c0 = lane, c1 = lane + 64, c2 = lane + 128, c3 = lane + 192;
  float acc0 = 0.f, acc1 = 0.f, acc2 = 0.f, acc3 = 0.f, rs = 0.f;
  float s0s;
  auto edgeop = [&](int2 ed) {
    unsigned w0 = (unsigned)ed.x;
    int e1 = (int)(w0 & 0xFFFFu);
    int t1 = (int)(w0 >> 16);
    int t2f = ed.y;
    float p = s0s + sdst[e1] + srel[t1];
    const unsigned short* rd = dstb + (size_t)e1 * 200;
    const float* r1 = relp + t1 * 200;
    float m0, m1, m2, m3;
    if (t2f) {
      int t2 = t2f - 1;
      p += srel[t2];
      const float* r2 = relp + t2 * 200;
      m0 = b2f(rd[c0]) + r1[c0] + r2[c0];
      m1 = b2f(rd[c1]) + r1[c1] + r2[c1];
      m2 = b2f(rd[c2]) + r1[c2] + r2[c2];
      m3 = (c3 < 200) ? b2f(rd[c3]) + r1[c3] + r2[c3] : 0.f;
    } else {
      m0 = b2f(rd[c0]) + r1[c0];
      m1 = b2f(rd[c1]) + r1[c1];
      m2 = b2f(rd[c2]) + r1[c2];
      m3 = (c3 < 200) ? b2f(rd[c3]) + r1[c3] : 0.f;
    }
    p = (p > 0.f) ? p : 0.2f * p;
    float ee = __expf(-p);
    rs += ee;
    acc0 += ee * m0; acc1 += ee * m1; acc2 += ee * m2; acc3 += ee * m3;
  };
  if (blockIdx.x < HBMAX) {
    int hidx = blockIdx.x;
    if (hidx >= cnts[1]) return;
    int node = heavyL[hidx];
    int s = offs[node], e = offs[node + 1];
    s0s = ssrc[node];
    int q = s + w;
    for (; q + 8 < e; q += 16) { edgeop(edata[q]); edgeop(edata[q + 8]); }
    if (q < e) edgeop(edata[q]);
    part[w][c0] = acc0; part[w][c1] = acc1; part[w][c2] = acc2;
    if (c3 < 200) part[w][c3] = acc3;
    if (lane == 0) part[w][200] = rs;
    __syncthreads();
    int t = threadIdx.x;
    if (t < 200) {
      float a = 0.f, r = 0.f;
      #pragma unroll
      for (int wv = 0; wv < 8; ++wv) { a += part[wv][t]; r += part[wv][200]; }
      float v = srcp[(size_t)node * 200 + t] + a / r;
      hout[(size_t)node * 200 + t] = (v > 0.f) ? v : expm1f(v);
    }
    return;
  }
  int widx = (blockIdx.x - HBMAX) * 8 + w;
  if (widx >= cnts[0]) return;
  int node = lightL[widx];
  int s = offs[node], e = offs[node + 1];
  s0s = ssrc[node];
  int q = s;
  for (; q + 1 < e; q += 2) { edgeop(edata[q]); edgeop(edata[q + 1]); }
  if (q < e) edgeop(edata[q]);
  bool has = (e > s);
  float inv = has ? 1.f / rs : 0.f;
  const float* sp = srcp + (size_t)node * 200;
  float* ho = hout + (size_t)node * 200;
  float v;
  v = has ? sp[c0] + acc0 * inv : 0.f; ho[c0] = (v > 0.f) ? v : expm1f(v);
  v = has ? sp[c1] + acc1 * inv : 0.f; ho[c1] = (v > 0.f) ? v : expm1f(v);
  v = has ? sp[c2] + acc2 * inv : 0.f; ho[c2] = (v > 0.f) ? v : expm1f(v);
  if (c3 < 200) {
    v = has ? sp[c3] + acc3 * inv : 0.f;
    ho[c3] = (v > 0.f) ? v : expm1f(v);
  }
}

// ---------------- pad xbf rows [NN, MP) ----------------
__global__ __launch_bounds__(256) void padx(unsigned short* __restrict__ xbf) {
  int i = blockIdx.x * 256 + threadIdx.x;
  if (i < (MP - NN) * 224) xbf[(size_t)NN * 224 + i] = 0;
}

// ---------------- mask scatter ----------------
__global__ __launch_bounds__(256) void maskset(const int* __restrict__ bi, float* __restrict__ maskA) {
  int t = blockIdx.x * 256 + threadIdx.x;
  if (t < BATCH) maskA[bi[t * 3 + 2]] = 1.0f;
}

// ---------------- final: out = l2norm(xw + mask*h2), in place ----------------
__global__ __launch_bounds__(256) void finalk2(const float* __restrict__ xw, const float* __restrict__ h2,
                                               const float* __restrict__ maskA, float* __restrict__ out) {
  int row  = blockIdx.x * 4 + (threadIdx.x >> 6);
  int lane = threadIdx.x & 63;
  if (row >= NN) return;
  float m = maskA[row];
  const float* xr = xw + (size_t)row * 200;
  const float* hr = h2 + (size_t)row * 200;
  int c0 = lane, c1 = lane + 64, c2 = lane + 128, c3 = lane + 192;
  float v0 = xr[c0] + m * hr[c0];
  float v1 = xr[c1] + m * hr[c1];
  float v2 = xr[c2] + m * hr[c2];
  float v3 = (c3 < 200) ? xr[c3] + m * hr[c3] : 0.f;
  float ss = v0 * v0 + v1 * v1 + v2 * v2 + v3 * v3;
  #pragma unroll
  for (int off = 1; off < 64; off <<= 1) ss += __shfl_xor(ss, off);
  float inv = 1.f / fmaxf(sqrtf(ss), 1e-12f);
  float* o = out + (size_t)row * 200;
  o[c0] = v0 * inv; o[c1] = v1 * inv; o[c2] = v2 * inv;
  if (c3 < 200) o[c3] = v3 * inv;
}

extern "C" void kernel_launch(void* const* d_in, const int* in_sizes, int n_in,
                              void* d_out, int out_size, void* d_ws, size_t ws_size,
                              hipStream_t stream) {
  (void)in_sizes; (void)n_in; (void)out_size; (void)ws_size;
  const float* ent      = (const float*)d_in[0];
  const float* rel      = (const float*)d_in[1];
  const float* a_heads  = (const float*)d_in[3];
  const float* a2_heads = (const float*)d_in[4];
  const float* W_gat    = (const float*)d_in[5];
  const float* a_out    = (const float*)d_in[6];
  const float* a2_out   = (const float*)d_in[7];
  const float* W_ent    = (const float*)d_in[8];
  const int* edge_list  = (const int*)d_in[9];
  const int* edge_type  = (const int*)d_in[10];
  const int* tin        = (const int*)d_in[11];
  const int* binp       = (const int*)d_in[12];

  float* out    = (float*)d_out;
  float* outrel = out + 10000000;     // (500,200)

  float* ws    = (float*)d_ws;
  float* bufS  = ws;                               // 10M f32: srcp1 -> srcp2 -> h2
  unsigned short* dstD = (unsigned short*)(ws + 10000000); // NN*200 bf16 (dstp1 then dstp2)
  float* relp1 = ws + 15000000;       // 100k
  float* relp2 = ws + 15100000;       // 100k
  float* ssrc1 = ws + 15200000;       // N*2
  float* sdst1 = ws + 15300000;       // N*2
  float* s2src = ws + 15400000;       // N
  float* s2dst = ws + 15450000;       // N
  float* srel1 = ws + 15500000;       // 1000
  float* s2rel = ws + 15501000;       // 500
  float* maskA = ws + 15502000;       // N
  unsigned short* x0nbf = (unsigned short*)(ws + 15560000); // MP*128 bf16
  unsigned short* xbf   = (unsigned short*)(ws + 18800000); // MP*224 bf16
  unsigned short* B1s   = (unsigned short*)(ws + 24450000); // 208*128
  unsigned short* B1d   = (unsigned short*)(ws + 24470000);
  unsigned short* Bxw   = (unsigned short*)(ws + 24490000);
  unsigned short* B2s   = (unsigned short*)(ws + 24510000); // 208*224
  unsigned short* B2d   = (unsigned short*)(ws + 24540000);
  int* ibase  = (int*)(ws + 24600000);
  int* deg    = ibase;                // 50k
  int* offs   = ibase + 50000;        // 50k+1
  int* pos    = ibase + 100016;       // 50k
  int* bsum   = ibase + 150016;       // 256
  int* cnts   = ibase + 150272;       // 2 (+pad)
  int* lightL = ibase + 150280;       // 50k
  int* heavyL = ibase + 200280;       // 50k (+pad)
  int2* edata = (int2*)(ibase + 250288); // 375k int2

  hipMemsetAsync(deg,   0, (size_t)NN * 4, stream);
  hipMemsetAsync(maskA, 0, (size_t)NN * 4, stream);
  hipMemsetAsync(cnts,  0, 8, stream);

  l2norm_bf16<<<12512, 256, 0, stream>>>(ent, x0nbf);

  // CSR + lists
  histk<<<(ETOT + 255) / 256, 256, 0, stream>>>(edge_list, tin, deg);
  scanA<<<196, 256, 0, stream>>>(deg, bsum, NN);
  scanB<<<1, 256, 0, stream>>>(bsum, 196);
  scanC<<<196, 256, 0, stream>>>(deg, bsum, offs, pos, NN, ETOT);
  scatterk<<<(ETOT + 255) / 256, 256, 0, stream>>>(edge_list, edge_type, tin, pos, edata);
  buildLists<<<196, 256, 0, stream>>>(offs, lightL, heavyL, cnts);

  // weight conversion
  convB1<<<104, 256, 0, stream>>>(a_heads, 0,   B1s);
  convB1<<<104, 256, 0, stream>>>(a_heads, 100, B1d);
  convBg<<<104, 256, 0, stream>>>(W_ent, 1, 200, 200, 100, 128, Bxw);
  convBg<<<182, 256, 0, stream>>>(a_out,       600, 1, 200, 200, 224, B2s);
  convBg<<<182, 256, 0, stream>>>(a_out + 200, 600, 1, 200, 200, 224, B2d);

  // layer-1 projections + xw, one 3-job launch
  {
    GJob js = {B1s, bufS, nullptr, a2_heads, ssrc1, 1};
    GJob jd = {B1d, nullptr, dstD, a2_heads, sdst1, 1};
    GJob jx = {Bxw, out, nullptr, nullptr, nullptr, 0};
    dim3 g(391, 3);
    gemm_multi<128><<<g, 256, 0, stream>>>(x0nbf, js, jd, jx, NN);
  }

  // rel projections (f32, small) + rel dots
  dim3 g2(2, 4);
  gemm2_f32<<<g2, 256, 0, stream>>>(rel, NRELS, 100, 100, a_heads + 200,         300, 1, relp1, 200, 100, 0);
  gemm2_f32<<<g2, 256, 0, stream>>>(rel, NRELS, 100, 100, a_heads + 30000 + 200, 300, 1, relp1, 200, 100, 100);
  dot2h<<<125, 256, 0, stream>>>(relp1, a2_heads, srel1, NRELS);

  gather1M<<<HBMAX + LB1, 512, 0, stream>>>(lightL, heavyL, cnts, offs, edata,
                                            bufS, dstD, relp1, ssrc1, sdst1, srel1, xbf);
  padx<<<42, 256, 0, stream>>>(xbf);

  // layer-2 projections, one 2-job launch (overwrites bufS/dstD)
  {
    GJob js = {B2s, bufS, nullptr, a2_out, s2src, 2};
    GJob jd = {B2d, nullptr, dstD, a2_out, s2dst, 2};
    GJob jz = {B2s, nullptr, nullptr, nullptr, nullptr, 0};
    dim3 g(391, 2);
    gemm_multi<224><<<g, 256, 0, stream>>>(xbf, js, jd, jz, NN);
  }

  // out_relation_1, relp2, rel dot
  dim3 g3(4, 4);
  gemm2_f32<<<g3, 256, 0, stream>>>(rel, NRELS, 100, 100, W_gat, 1, 200, outrel, 200, 200, 0);
  gemm2_f32<<<g3, 256, 0, stream>>>(outrel, NRELS, 200, 200, a_out + 400, 600, 1, relp2, 200, 200, 0);
  dot1<<<125, 256, 0, stream>>>(relp2, a2_out, s2rel, NRELS);

  maskset<<<256, 256, 0, stream>>>(binp, maskA);

  gather2M<<<HBMAX + LB1, 512, 0, stream>>>(lightL, heavyL, cnts, offs, edata,
                                            bufS, dstD, relp2, s2src, s2dst, s2rel, bufS);

  finalk2<<<12500, 256, 0, stream>>>(out, bufS, maskA, out);
}

// Round 8
// 586.852 us; speedup vs baseline: 2.1627x; 1.0916x over previous
//
#include <hip/hip_runtime.h>
#include <math.h>

#define NN    50000
#define MP    50048    // padded rows (391*128)
#define NEDGE 250000
#define NHOPE 125000
#define ETOT  375000
#define NRELS 500
#define BATCH 65536
#define LB1   6250     // light blocks (8 waves each -> 50000 waves)
#define HBMAX 5769     // max heavy nodes (deg>64): 375000/65

typedef __attribute__((ext_vector_type(8))) short bf16x8;
typedef __attribute__((ext_vector_type(4))) float f32x4;

__device__ __forceinline__ unsigned short bf16rne(float f) {
  unsigned u = __float_as_uint(f);
  unsigned r = (u + 0x7FFFu + ((u >> 16) & 1u)) >> 16;
  return (unsigned short)r;
}
__device__ __forceinline__ float b2f(unsigned short u) {
  return __uint_as_float(((unsigned)u) << 16);
}

struct GJob {
  const unsigned short* B;   // 208 x KP bf16
  float* Cf;                 // f32 out (ld 200) or null
  unsigned short* Cbf;       // bf16 out (ld 200) or null
  const float* a2;           // 200 floats or null
  float* dot;                // per-row scalar(s) or null
  int dotmode;               // 1 = split at 100 (two heads), 2 = single sum
};

// ---------------- l2norm -> bf16 padded (MP x 128) ----------------
__global__ __launch_bounds__(256) void l2norm_bf16(const float* __restrict__ in,
                                                   unsigned short* __restrict__ out) {
  int row  = blockIdx.x * 4 + (threadIdx.x >> 6);
  int lane = threadIdx.x & 63;
  if (row >= MP) return;
  unsigned short* o = out + (size_t)row * 128;
  if (row >= NN) { o[lane] = 0; o[lane + 64] = 0; return; }
  const float* r = in + (size_t)row * 100;
  float v0 = r[lane];
  float v1 = (lane + 64 < 100) ? r[lane + 64] : 0.f;
  float ss = v0 * v0 + v1 * v1;
  #pragma unroll
  for (int off = 1; off < 64; off <<= 1) ss += __shfl_xor(ss, off);
  float inv = 1.f / fmaxf(sqrtf(ss), 1e-12f);
  o[lane] = bf16rne(v0 * inv);
  o[lane + 64] = (lane + 64 < 100) ? bf16rne(v1 * inv) : (unsigned short)0;
}

// ---------------- multi-job bf16 MFMA GEMM with fused epilogue ----------------
template<int KP>
__global__ __launch_bounds__(256) void gemm_multi(const unsigned short* __restrict__ A,
                                                  GJob j0, GJob j1, GJob j2, int M) {
  GJob jb = (blockIdx.y == 0) ? j0 : ((blockIdx.y == 1) ? j1 : j2);
  int wave = threadIdx.x >> 6, lane = threadIdx.x & 63;
  int rb = blockIdx.x * 128 + wave * 32;
  int rl = lane & 15;
  int kq = (lane >> 4) * 8;
  const unsigned short* a0p = A + (size_t)(rb + rl) * KP + kq;
  const unsigned short* a1p = a0p + (size_t)16 * KP;
  const unsigned short* bp  = jb.B + (size_t)rl * KP + kq;
  f32x4 acc[2][13];
  #pragma unroll
  for (int i = 0; i < 2; ++i)
    #pragma unroll
    for (int t = 0; t < 13; ++t) acc[i][t] = (f32x4){0.f, 0.f, 0.f, 0.f};
  #pragma unroll 2
  for (int ks = 0; ks < KP; ks += 32) {
    bf16x8 a0 = *(const bf16x8*)(a0p + ks);
    bf16x8 a1 = *(const bf16x8*)(a1p + ks);
    #pragma unroll
    for (int t = 0; t < 13; ++t) {
      bf16x8 b = *(const bf16x8*)(bp + (size_t)t * 16 * KP + ks);
      acc[0][t] = __builtin_amdgcn_mfma_f32_16x16x32_bf16(a0, b, acc[0][t], 0, 0, 0);
      acc[1][t] = __builtin_amdgcn_mfma_f32_16x16x32_bf16(a1, b, acc[1][t], 0, 0, 0);
    }
  }
  int rg = (lane >> 4) * 4;
  if (jb.Cf) {
    #pragma unroll
    for (int rt = 0; rt < 2; ++rt) {
      int row0 = rb + rt * 16 + rg;
      #pragma unroll
      for (int t = 0; t < 13; ++t) {
        int col = t * 16 + rl;
        if (col < 200) {
          #pragma unroll
          for (int g = 0; g < 4; ++g) {
            int row = row0 + g;
            if (row < M) jb.Cf[(size_t)row * 200 + col] = acc[rt][t][g];
          }
        }
      }
    }
  }
  if (jb.Cbf) {
    #pragma unroll
    for (int rt = 0; rt < 2; ++rt) {
      int row0 = rb + rt * 16 + rg;
      #pragma unroll
      for (int t = 0; t < 13; ++t) {
        int col = t * 16 + rl;
        if (col < 200) {
          #pragma unroll
          for (int g = 0; g < 4; ++g) {
            int row = row0 + g;
            if (row < M) jb.Cbf[(size_t)row * 200 + col] = bf16rne(acc[rt][t][g]);
          }
        }
      }
    }
  }
  if (jb.dot) {
    #pragma unroll
    for (int rt = 0; rt < 2; ++rt) {
      float p0[4] = {0.f, 0.f, 0.f, 0.f}, p1[4] = {0.f, 0.f, 0.f, 0.f};
      #pragma unroll
      for (int t = 0; t < 13; ++t) {
        int col = t * 16 + rl;
        float av = (col < 200) ? jb.a2[col] : 0.f;
        bool lo = (col < 100);
        #pragma unroll
        for (int g = 0; g < 4; ++g) {
          float v = acc[rt][t][g] * av;
          if (lo) p0[g] += v; else p1[g] += v;
        }
      }
      #pragma unroll
      for (int off = 1; off < 16; off <<= 1) {
        #pragma unroll
        for (int g = 0; g < 4; ++g) {
          p0[g] += __shfl_xor(p0[g], off);
          p1[g] += __shfl_xor(p1[g], off);
        }
      }
      if (rl == 0) {
        int row0 = rb + rt * 16 + rg;
        #pragma unroll
        for (int g = 0; g < 4; ++g) {
          int row = row0 + g;
          if (row < M) {
            if (jb.dotmode == 1) { jb.dot[row * 2] = p0[g]; jb.dot[row * 2 + 1] = p1[g]; }
            else                 { jb.dot[row] = p0[g] + p1[g]; }
          }
        }
      }
    }
  }
}

// ---------------- weight conversion to bf16 k-major padded ----------------
__global__ __launch_bounds__(256) void convB1(const float* __restrict__ ah, int koff,
                                              unsigned short* __restrict__ dst) {
  int idx = blockIdx.x * 256 + threadIdx.x;
  if (idx >= 208 * 128) return;
  int j = idx >> 7, k = idx & 127;
  float v = 0.f;
  if (j < 200 && k < 100) {
    const float* s = ah + ((j < 100) ? 0 : 30000) + (j % 100) * 300 + koff;
    v = s[k];
  }
  dst[idx] = bf16rne(v);
}

__global__ __launch_bounds__(256) void convBg(const float* __restrict__ src, int wsj, int wsk,
                                              int rows, int K, int Kp,
                                              unsigned short* __restrict__ dst) {
  int idx = blockIdx.x * 256 + threadIdx.x;
  if (idx >= 208 * Kp) return;
  int j = idx / Kp, k = idx - j * Kp;
  float v = (j < rows && k < K) ? src[(size_t)j * wsj + (size_t)k * wsk] : 0.f;
  dst[idx] = bf16rne(v);
}

// ---------------- f32 GEMM (small, rel matrices) ----------------
__global__ __launch_bounds__(256) void gemm2_f32(const float* __restrict__ A, int M, int Kd, int lda,
                                                 const float* __restrict__ W, int wsj, int wsk,
                                                 float* __restrict__ C, int ldc, int Ncols, int col0) {
  __shared__ float As[16][132];
  __shared__ float Bs[16][68];
  int tid = threadIdx.x;
  int tx = tid & 15, ty = tid >> 4;
  int row0 = blockIdx.y * 128;
  int colb = blockIdx.x * 64;
  float acc[8][4];
  #pragma unroll
  for (int i = 0; i < 8; ++i)
    #pragma unroll
    for (int j = 0; j < 4; ++j) acc[i][j] = 0.f;
  for (int kt = 0; kt < Kd; kt += 16) {
    #pragma unroll
    for (int l = 0; l < 8; ++l) {
      int idx = tid + l * 256;
      int m = idx >> 4, k = idx & 15;
      int gm = row0 + m, gk = kt + k;
      As[k][m] = (gm < M && gk < Kd) ? A[(size_t)gm * lda + gk] : 0.f;
    }
    #pragma unroll
    for (int l = 0; l < 4; ++l) {
      int idx = tid + l * 256;
      int j = idx >> 4, k = idx & 15;
      int gj = colb + j, gk = kt + k;
      Bs[k][j] = (gj < Ncols && gk < Kd) ? W[(size_t)gj * wsj + (size_t)gk * wsk] : 0.f;
    }
    __syncthreads();
    #pragma unroll
    for (int k = 0; k < 16; ++k) {
      float4 bv = *(const float4*)&Bs[k][tx * 4];
      float4 a0 = *(const float4*)&As[k][ty * 8];
      float4 a1 = *(const float4*)&As[k][ty * 8 + 4];
      float av[8] = {a0.x, a0.y, a0.z, a0.w, a1.x, a1.y, a1.z, a1.w};
      float bb[4] = {bv.x, bv.y, bv.z, bv.w};
      #pragma unroll
      for (int i = 0; i < 8; ++i)
        #pragma unroll
        for (int j = 0; j < 4; ++j)
          acc[i][j] += av[i] * bb[j];
    }
    __syncthreads();
  }
  int gj0 = colb + tx * 4;
  #pragma unroll
  for (int i = 0; i < 8; ++i) {
    int gm = row0 + ty * 8 + i;
    if (gm >= M) continue;
    float* cp = C + (size_t)gm * ldc + col0;
    #pragma unroll
    for (int j = 0; j < 4; ++j) if (gj0 + j < Ncols) cp[gj0 + j] = acc[i][j];
  }
}

// ---------------- per-row dots (rel rows only) ----------------
__global__ __launch_bounds__(256) void dot2h(const float* __restrict__ P, const float* __restrict__ a2,
                                             float* __restrict__ outp, int M) {
  int row  = blockIdx.x * 4 + (threadIdx.x >> 6);
  int lane = threadIdx.x & 63;
  if (row >= M) return;
  const float* pr = P + (size_t)row * 200;
  float s0 = 0.f, s1 = 0.f;
  for (int k = lane; k < 100; k += 64) {
    s0 += pr[k] * a2[k];
    s1 += pr[100 + k] * a2[100 + k];
  }
  #pragma unroll
  for (int off = 1; off < 64; off <<= 1) { s0 += __shfl_xor(s0, off); s1 += __shfl_xor(s1, off); }
  if (lane == 0) { outp[row * 2] = s0; outp[row * 2 + 1] = s1; }
}

__global__ __launch_bounds__(256) void dot1(const float* __restrict__ P, const float* __restrict__ a2,
                                            float* __restrict__ outp, int M) {
  int row  = blockIdx.x * 4 + (threadIdx.x >> 6);
  int lane = threadIdx.x & 63;
  if (row >= M) return;
  const float* pr = P + (size_t)row * 200;
  float s = 0.f;
  for (int k = lane; k < 200; k += 64) s += pr[k] * a2[k];
  #pragma unroll
  for (int off = 1; off < 64; off <<= 1) s += __shfl_xor(s, off);
  if (lane == 0) outp[row] = s;
}

// ---------------- CSR build ----------------
__global__ __launch_bounds__(256) void histk(const int* __restrict__ el, const int* __restrict__ tin,
                                             int* __restrict__ deg) {
  int i = blockIdx.x * 256 + threadIdx.x;
  if (i >= ETOT) return;
  int e0 = (i < NEDGE) ? el[i] : tin[(size_t)(i - NEDGE) * 4 + 3];
  atomicAdd(&deg[e0], 1);
}

__global__ __launch_bounds__(256) void scanA(const int* __restrict__ deg, int* __restrict__ bsum, int n) {
  __shared__ int s[256];
  int t = threadIdx.x;
  int i = blockIdx.x * 256 + t;
  s[t] = (i < n) ? deg[i] : 0;
  __syncthreads();
  for (int off = 128; off > 0; off >>= 1) {
    if (t < off) s[t] += s[t + off];
    __syncthreads();
  }
  if (t == 0) bsum[blockIdx.x] = s[0];
}

__global__ __launch_bounds__(256) void scanB(int* __restrict__ bsum, int nb) {
  __shared__ int s[256];
  int t = threadIdx.x;
  int v = (t < nb) ? bsum[t] : 0;
  s[t] = v;
  __syncthreads();
  for (int off = 1; off < 256; off <<= 1) {
    int add = (t >= off) ? s[t - off] : 0;
    __syncthreads();
    s[t] += add;
    __syncthreads();
  }
  if (t < nb) bsum[t] = s[t] - v;  // exclusive
}

__global__ __launch_bounds__(256) void scanC(const int* __restrict__ deg, const int* __restrict__ bsum,
                                             int* __restrict__ offs, int* __restrict__ pos, int n, int total) {
  __shared__ int s[256];
  int t = threadIdx.x;
  int i = blockIdx.x * 256 + t;
  int v = (i < n) ? deg[i] : 0;
  s[t] = v;
  __syncthreads();
  for (int off = 1; off < 256; off <<= 1) {
    int add = (t >= off) ? s[t - off] : 0;
    __syncthreads();
    s[t] += add;
    __syncthreads();
  }
  if (i < n) {
    int e = bsum[blockIdx.x] + s[t] - v;
    offs[i] = e;
    pos[i]  = e;
  }
  if (i == 0) offs[n] = total;
}

__global__ __launch_bounds__(256) void scatterk(const int* __restrict__ el, const int* __restrict__ et,
                                                const int* __restrict__ tin,
                                                int* __restrict__ pos, int2* __restrict__ edata) {
  int i = blockIdx.x * 256 + threadIdx.x;
  if (i >= ETOT) return;
  int e0, e1, t1, t2f;
  if (i < NEDGE) {
    e0 = el[i]; e1 = el[NEDGE + i]; t1 = et[i]; t2f = 0;
  } else {
    const int* q = tin + (size_t)(i - NEDGE) * 4;
    e0 = q[3]; e1 = q[0]; t1 = q[1]; t2f = q[2] + 1;
  }
  int slot = atomicAdd(&pos[e0], 1);
  edata[slot] = make_int2(e1 | (t1 << 16), t2f);
}

// wave-aggregated list append
__global__ __launch_bounds__(256) void buildLists(const int* __restrict__ offs,
                                                  int* __restrict__ lightL, int* __restrict__ heavyL,
                                                  int* __restrict__ cnts) {
  int i = blockIdx.x * 256 + threadIdx.x;
  int lane = threadIdx.x & 63;
  bool valid = (i < NN);
  int d = valid ? (offs[i + 1] - offs[i]) : 0;
  bool heavy = valid && (d > 64);
  bool light = valid && (d <= 64);
  unsigned long long mh = __ballot(heavy);
  unsigned long long ml = __ballot(light);
  unsigned long long below = (1ULL << lane) - 1ULL;
  int bh = 0, bl = 0;
  if (lane == 0) {
    if (mh) bh = atomicAdd(&cnts[1], __popcll(mh));
    if (ml) bl = atomicAdd(&cnts[0], __popcll(ml));
  }
  bh = __shfl(bh, 0);
  bl = __shfl(bl, 0);
  if (heavy) heavyL[bh + __popcll(mh & below)] = i;
  if (light) lightL[bl + __popcll(ml & below)] = i;
}

// ---------------- merged layer-1 gather (heavy-first), vectorized lanes ----------------
// lane l<50 owns cols 4l..4l+3 (head0 for l<25, head1 for l>=25)
__global__ __launch_bounds__(512) void gather1M(const int* __restrict__ lightL, const int* __restrict__ heavyL,
    const int* __restrict__ cnts, const int* __restrict__ offs, const int2* __restrict__ edata,
    const float* __restrict__ srcp, const unsigned short* __restrict__ dstb, const float* __restrict__ relp,
    const float* __restrict__ ssrc, const float* __restrict__ sdst, const float* __restrict__ srel,
    unsigned short* __restrict__ xbf) {
  __shared__ float part[8][208];
  int w = threadIdx.x >> 6, lane = threadIdx.x & 63;
  bool act = lane < 50;
  int cb = lane * 4;
  float a0 = 0.f, a1 = 0.f, a2v = 0.f, a3 = 0.f, rs0 = 0.f, rs1 = 0.f;
  float s00, s01;
  bool hd0 = (cb < 100);
  auto edgeop = [&](int2 ed) {
    unsigned w0 = (unsigned)ed.x;
    int e1 = (int)(w0 & 0xFFFFu);
    int t1 = (int)(w0 >> 16);
    int t2f = ed.y;
    float2 sd = *(const float2*)(sdst + e1 * 2);
    float p0 = s00 + sd.x + srel[t1 * 2];
    float p1 = s01 + sd.y + srel[t1 * 2 + 1];
    float m0 = 0.f, m1 = 0.f, m2 = 0.f, m3 = 0.f;
    if (act) {
      ushort4 dv = *(const ushort4*)(dstb + (size_t)e1 * 200 + cb);
      float4 r1v = *(const float4*)(relp + (size_t)t1 * 200 + cb);
      m0 = b2f(dv.x) + r1v.x;
      m1 = b2f(dv.y) + r1v.y;
      m2 = b2f(dv.z) + r1v.z;
      m3 = b2f(dv.w) + r1v.w;
    }
    if (t2f) {
      int t2 = t2f - 1;
      p0 += srel[t2 * 2]; p1 += srel[t2 * 2 + 1];
      if (act) {
        float4 r2v = *(const float4*)(relp + (size_t)t2 * 200 + cb);
        m0 += r2v.x; m1 += r2v.y; m2 += r2v.z; m3 += r2v.w;
      }
    }
    p0 = (p0 > 0.f) ? p0 : 0.2f * p0;
    p1 = (p1 > 0.f) ? p1 : 0.2f * p1;
    float ee0 = __expf(-p0), ee1 = __expf(-p1);
    rs0 += ee0; rs1 += ee1;
    float ee = hd0 ? ee0 : ee1;
    a0 += ee * m0; a1 += ee * m1; a2v += ee * m2; a3 += ee * m3;
  };
  if (blockIdx.x < HBMAX) {
    int hidx = blockIdx.x;
    if (hidx >= cnts[1]) return;
    int node = heavyL[hidx];
    int s = offs[node], e = offs[node + 1];
    s00 = ssrc[node * 2]; s01 = ssrc[node * 2 + 1];
    int q = s + w;
    for (; q + 8 < e; q += 16) { edgeop(edata[q]); edgeop(edata[q + 8]); }
    if (q < e) edgeop(edata[q]);
    if (act) { part[w][cb] = a0; part[w][cb + 1] = a1; part[w][cb + 2] = a2v; part[w][cb + 3] = a3; }
    if (lane == 0) { part[w][200] = rs0; part[w][201] = rs1; }
    __syncthreads();
    int t = threadIdx.x;
    if (t < 224) {
      unsigned short outv = 0;
      if (t < 200) {
        float a = 0.f, r0 = 0.f, r1 = 0.f;
        #pragma unroll
        for (int wv = 0; wv < 8; ++wv) { a += part[wv][t]; r0 += part[wv][200]; r1 += part[wv][201]; }
        float inv = (t < 100) ? 1.f / r0 : 1.f / r1;
        float v = srcp[(size_t)node * 200 + t] + a * inv;
        v = (v > 0.f) ? v : expm1f(v);
        outv = bf16rne(v);
      }
      xbf[(size_t)node * 224 + t] = outv;
    }
    return;
  }
  int widx = (blockIdx.x - HBMAX) * 8 + w;
  if (widx >= cnts[0]) return;
  int node = lightL[widx];
  int s = offs[node], e = offs[node + 1];
  s00 = ssrc[node * 2]; s01 = ssrc[node * 2 + 1];
  int q = s;
  for (; q + 1 < e; q += 2) { edgeop(edata[q]); edgeop(edata[q + 1]); }
  if (q < e) edgeop(edata[q]);
  bool has = (e > s);
  unsigned short* xo = xbf + (size_t)node * 224;
  if (act) {
    float inv = has ? (hd0 ? 1.f / rs0 : 1.f / rs1) : 0.f;
    const float* sp = srcp + (size_t)node * 200 + cb;
    float4 sv = *(const float4*)sp;
    float v0 = has ? sv.x + a0 * inv : 0.f;
    float v1 = has ? sv.y + a1 * inv : 0.f;
    float v2 = has ? sv.z + a2v * inv : 0.f;
    float v3 = has ? sv.w + a3 * inv : 0.f;
    v0 = (v0 > 0.f) ? v0 : expm1f(v0);
    v1 = (v1 > 0.f) ? v1 : expm1f(v1);
    v2 = (v2 > 0.f) ? v2 : expm1f(v2);
    v3 = (v3 > 0.f) ? v3 : expm1f(v3);
    ushort4 ov = {bf16rne(v0), bf16rne(v1), bf16rne(v2), bf16rne(v3)};
    *(ushort4*)(xo + cb) = ov;
  } else if (lane < 56) {
    ushort4 z = {0, 0, 0, 0};
    *(ushort4*)(xo + cb) = z;
  }
}

// ---------------- merged layer-2 gather (heavy-first), vectorized lanes ----------------
__global__ __launch_bounds__(512) void gather2M(const int* __restrict__ lightL, const int* __restrict__ heavyL,
    const int* __restrict__ cnts, const int* __restrict__ offs, const int2* __restrict__ edata,
    const float* __restrict__ srcp, const unsigned short* __restrict__ dstb, const float* __restrict__ relp,
    const float* __restrict__ ssrc, const float* __restrict__ sdst, const float* __restrict__ srel,
    float* __restrict__ hout) {
  __shared__ float part[8][208];
  int w = threadIdx.x >> 6, lane = threadIdx.x & 63;
  bool act = lane < 50;
  int cb = lane * 4;
  float a0 = 0.f, a1 = 0.f, a2v = 0.f, a3 = 0.f, rs = 0.f;
  float s0s;
  auto edgeop = [&](int2 ed) {
    unsigned w0 = (unsigned)ed.x;
    int e1 = (int)(w0 & 0xFFFFu);
    int t1 = (int)(w0 >> 16);
    int t2f = ed.y;
    float p = s0s + sdst[e1] + srel[t1];
    float m0 = 0.f, m1 = 0.f, m2 = 0.f, m3 = 0.f;
    if (act) {
      ushort4 dv = *(const ushort4*)(dstb + (size_t)e1 * 200 + cb);
      float4 r1v = *(const float4*)(relp + (size_t)t1 * 200 + cb);
      m0 = b2f(dv.x) + r1v.x;
      m1 = b2f(dv.y) + r1v.y;
      m2 = b2f(dv.z) + r1v.z;
      m3 = b2f(dv.w) + r1v.w;
    }
    if (t2f) {
      int t2 = t2f - 1;
      p += srel[t2];
      if (act) {
        float4 r2v = *(const float4*)(relp + (size_t)t2 * 200 + cb);
        m0 += r2v.x; m1 += r2v.y; m2 += r2v.z; m3 += r2v.w;
      }
    }
    p = (p > 0.f) ? p : 0.2f * p;
    float ee = __expf(-p);
    rs += ee;
    a0 += ee * m0; a1 += ee * m1; a2v += ee * m2; a3 += ee * m3;
  };
  if (blockIdx.x < HBMAX) {
    int hidx = blockIdx.x;
    if (hidx >= cnts[1]) return;
    int node = heavyL[hidx];
    int s = offs[node], e = offs[node + 1];
    s0s = ssrc[node];
    int q = s + w;
    for (; q + 8 < e; q += 16) { edgeop(edata[q]); edgeop(edata[q + 8]); }
    if (q < e) edgeop(edata[q]);
    if (act) { part[w][cb] = a0; part[w][cb + 1] = a1; part[w][cb + 2] = a2v; part[w][cb + 3] = a3; }
    if (lane == 0) part[w][200] = rs;
    __syncthreads();
    int t = threadIdx.x;
    if (t < 200) {
      float a = 0.f, r = 0.f;
      #pragma unroll
      for (int wv = 0; wv < 8; ++wv) { a += part[wv][t]; r += part[wv][200]; }
      float v = srcp[(size_t)node * 200 + t] + a / r;
      hout[(size_t)node * 200 + t] = (v > 0.f) ? v : expm1f(v);
    }
    return;
  }
  int widx = (blockIdx.x - HBMAX) * 8 + w;
  if (widx >= cnts[0]) return;
  int node = lightL[widx];
  int s = offs[node], e = offs[node + 1];
  s0s = ssrc[node];
  int q = s;
  for (; q + 1 < e; q += 2) { edgeop(edata[q]); edgeop(edata[q + 1]); }
  if (q < e) edgeop(edata[q]);
  if (!act) return;
  bool has = (e > s);
  float inv = has ? 1.f / rs : 0.f;
  const float* sp = srcp + (size_t)node * 200 + cb;
  float4 sv = *(const float4*)sp;
  float v0 = has ? sv.x + a0 * inv : 0.f;
  float v1 = has ? sv.y + a1 * inv : 0.f;
  float v2 = has ? sv.z + a2v * inv : 0.f;
  float v3 = has ? sv.w + a3 * inv : 0.f;
  v0 = (v0 > 0.f) ? v0 : expm1f(v0);
  v1 = (v1 > 0.f) ? v1 : expm1f(v1);
  v2 = (v2 > 0.f) ? v2 : expm1f(v2);
  v3 = (v3 > 0.f) ? v3 : expm1f(v3);
  float4 ov = {v0, v1, v2, v3};
  *(float4*)(hout + (size_t)node * 200 + cb) = ov;
}

// ---------------- pad xbf rows [NN, MP) ----------------
__global__ __launch_bounds__(256) void padx(unsigned short* __restrict__ xbf) {
  int i = blockIdx.x * 256 + threadIdx.x;
  if (i < (MP - NN) * 224) xbf[(size_t)NN * 224 + i] = 0;
}

// ---------------- mask scatter ----------------
__global__ __launch_bounds__(256) void maskset(const int* __restrict__ bi, float* __restrict__ maskA) {
  int t = blockIdx.x * 256 + threadIdx.x;
  if (t < BATCH) maskA[bi[t * 3 + 2]] = 1.0f;
}

// ---------------- final: out = l2norm(xw + mask*h2), in place ----------------
__global__ __launch_bounds__(256) void finalk2(const float* __restrict__ xw, const float* __restrict__ h2,
                                               const float* __restrict__ maskA, float* __restrict__ out) {
  int row  = blockIdx.x * 4 + (threadIdx.x >> 6);
  int lane = threadIdx.x & 63;
  if (row >= NN) return;
  float m = maskA[row];
  const float* xr = xw + (size_t)row * 200;
  const float* hr = h2 + (size_t)row * 200;
  int c0 = lane, c1 = lane + 64, c2 = lane + 128, c3 = lane + 192;
  float v0 = xr[c0] + m * hr[c0];
  float v1 = xr[c1] + m * hr[c1];
  float v2 = xr[c2] + m * hr[c2];
  float v3 = (c3 < 200) ? xr[c3] + m * hr[c3] : 0.f;
  float ss = v0 * v0 + v1 * v1 + v2 * v2 + v3 * v3;
  #pragma unroll
  for (int off = 1; off < 64; off <<= 1) ss += __shfl_xor(ss, off);
  float inv = 1.f / fmaxf(sqrtf(ss), 1e-12f);
  float* o = out + (size_t)row * 200;
  o[c0] = v0 * inv; o[c1] = v1 * inv; o[c2] = v2 * inv;
  if (c3 < 200) o[c3] = v3 * inv;
}

extern "C" void kernel_launch(void* const* d_in, const int* in_sizes, int n_in,
                              void* d_out, int out_size, void* d_ws, size_t ws_size,
                              hipStream_t stream) {
  (void)in_sizes; (void)n_in; (void)out_size; (void)ws_size;
  const float* ent      = (const float*)d_in[0];
  const float* rel      = (const float*)d_in[1];
  const float* a_heads  = (const float*)d_in[3];
  const float* a2_heads = (const float*)d_in[4];
  const float* W_gat    = (const float*)d_in[5];
  const float* a_out    = (const float*)d_in[6];
  const float* a2_out   = (const float*)d_in[7];
  const float* W_ent    = (const float*)d_in[8];
  const int* edge_list  = (const int*)d_in[9];
  const int* edge_type  = (const int*)d_in[10];
  const int* tin        = (const int*)d_in[11];
  const int* binp       = (const int*)d_in[12];

  float* out    = (float*)d_out;
  float* outrel = out + 10000000;     // (500,200)

  float* ws    = (float*)d_ws;
  float* bufS  = ws;                               // 10M f32: srcp1 -> srcp2 -> h2
  unsigned short* dstD = (unsigned short*)(ws + 10000000); // NN*200 bf16 (dstp1 then dstp2)
  float* relp1 = ws + 15000000;       // 100k
  float* relp2 = ws + 15100000;       // 100k
  float* ssrc1 = ws + 15200000;       // N*2
  float* sdst1 = ws + 15300000;       // N*2
  float* s2src = ws + 15400000;       // N
  float* s2dst = ws + 15450000;       // N
  float* srel1 = ws + 15500000;       // 1000
  float* s2rel = ws + 15501000;       // 500
  float* maskA = ws + 15502000;       // N
  unsigned short* x0nbf = (unsigned short*)(ws + 15560000); // MP*128 bf16
  unsigned short* xbf   = (unsigned short*)(ws + 18800000); // MP*224 bf16
  unsigned short* B1s   = (unsigned short*)(ws + 24450000); // 208*128
  unsigned short* B1d   = (unsigned short*)(ws + 24470000);
  unsigned short* Bxw   = (unsigned short*)(ws + 24490000);
  unsigned short* B2s   = (unsigned short*)(ws + 24510000); // 208*224
  unsigned short* B2d   = (unsigned short*)(ws + 24540000);
  int* ibase  = (int*)(ws + 24600000);
  int* deg    = ibase;                // 50k
  int* offs   = ibase + 50000;        // 50k+1
  int* pos    = ibase + 100016;       // 50k
  int* bsum   = ibase + 150016;       // 256
  int* cnts   = ibase + 150272;       // 2 (+pad)
  int* lightL = ibase + 150280;       // 50k
  int* heavyL = ibase + 200280;       // 50k (+pad)
  int2* edata = (int2*)(ibase + 250288); // 375k int2

  hipMemsetAsync(deg,   0, (size_t)NN * 4, stream);
  hipMemsetAsync(maskA, 0, (size_t)NN * 4, stream);
  hipMemsetAsync(cnts,  0, 8, stream);

  l2norm_bf16<<<12512, 256, 0, stream>>>(ent, x0nbf);

  // CSR + lists
  histk<<<(ETOT + 255) / 256, 256, 0, stream>>>(edge_list, tin, deg);
  scanA<<<196, 256, 0, stream>>>(deg, bsum, NN);
  scanB<<<1, 256, 0, stream>>>(bsum, 196);
  scanC<<<196, 256, 0, stream>>>(deg, bsum, offs, pos, NN, ETOT);
  scatterk<<<(ETOT + 255) / 256, 256, 0, stream>>>(edge_list, edge_type, tin, pos, edata);
  buildLists<<<196, 256, 0, stream>>>(offs, lightL, heavyL, cnts);

  // weight conversion
  convB1<<<104, 256, 0, stream>>>(a_heads, 0,   B1s);
  convB1<<<104, 256, 0, stream>>>(a_heads, 100, B1d);
  convBg<<<104, 256, 0, stream>>>(W_ent, 1, 200, 200, 100, 128, Bxw);
  convBg<<<182, 256, 0, stream>>>(a_out,       600, 1, 200, 200, 224, B2s);
  convBg<<<182, 256, 0, stream>>>(a_out + 200, 600, 1, 200, 200, 224, B2d);

  // layer-1 projections + xw, one 3-job launch
  {
    GJob js = {B1s, bufS, nullptr, a2_heads, ssrc1, 1};
    GJob jd = {B1d, nullptr, dstD, a2_heads, sdst1, 1};
    GJob jx = {Bxw, out, nullptr, nullptr, nullptr, 0};
    dim3 g(391, 3);
    gemm_multi<128><<<g, 256, 0, stream>>>(x0nbf, js, jd, jx, NN);
  }

  // rel projections (f32, small) + rel dots
  dim3 g2(2, 4);
  gemm2_f32<<<g2, 256, 0, stream>>>(rel, NRELS, 100, 100, a_heads + 200,         300, 1, relp1, 200, 100, 0);
  gemm2_f32<<<g2, 256, 0, stream>>>(rel, NRELS, 100, 100, a_heads + 30000 + 200, 300, 1, relp1, 200, 100, 100);
  dot2h<<<125, 256, 0, stream>>>(relp1, a2_heads, srel1, NRELS);

  gather1M<<<HBMAX + LB1, 512, 0, stream>>>(lightL, heavyL, cnts, offs, edata,
                                            bufS, dstD, relp1, ssrc1, sdst1, srel1, xbf);
  padx<<<42, 256, 0, stream>>>(xbf);

  // layer-2 projections, one 2-job launch (overwrites bufS/dstD)
  {
    GJob js = {B2s, bufS, nullptr, a2_out, s2src, 2};
    GJob jd = {B2d, nullptr, dstD, a2_out, s2dst, 2};
    GJob jz = {B2s, nullptr, nullptr, nullptr, nullptr, 0};
    dim3 g(391, 2);
    gemm_multi<224><<<g, 256, 0, stream>>>(xbf, js, jd, jz, NN);
  }

  // out_relation_1, relp2, rel dot
  dim3 g3(4, 4);
  gemm2_f32<<<g3, 256, 0, stream>>>(rel, NRELS, 100, 100, W_gat, 1, 200, outrel, 200, 200, 0);
  gemm2_f32<<<g3, 256, 0, stream>>>(outrel, NRELS, 200, 200, a_out + 400, 600, 1, relp2, 200, 200, 0);
  dot1<<<125, 256, 0, stream>>>(relp2, a2_out, s2rel, NRELS);

  maskset<<<256, 256, 0, stream>>>(binp, maskA);

  gather2M<<<HBMAX + LB1, 512, 0, stream>>>(lightL, heavyL, cnts, offs, edata,
                                            bufS, dstD, relp2, s2src, s2dst, s2rel, bufS);

  finalk2<<<12500, 256, 0, stream>>>(out, bufS, maskA, out);
}